// Round 13
// baseline (2672.638 us; speedup 1.0000x reference)
//
#include <hip/hip_runtime.h>

typedef __attribute__((ext_vector_type(8))) short bf16x8;
typedef __attribute__((ext_vector_type(4))) float f32x4;
typedef __attribute__((ext_vector_type(2))) float f32x2;
typedef __attribute__((ext_vector_type(4))) unsigned int u32x4;
typedef __attribute__((ext_vector_type(2))) unsigned int u32x2;
typedef __attribute__((ext_vector_type(4))) int i32x4;

#define DEV static __device__ __forceinline__

DEV unsigned short f2bf(float x){
  unsigned u = __float_as_uint(x);
  u += 0x7fffu + ((u >> 16) & 1u);
  return (unsigned short)(u >> 16);
}
DEV float bf2f(unsigned short b){ return __uint_as_float(((unsigned)b) << 16); }

DEV int swz8(int row){ return (row + (row >> 3)) & 7; }
DEV int swzb(int row, int cb){ return cb ^ (swz8(row) << 4); }
DEV int loff(int row, int cb){ return row * 128 + swzb(row, cb); }

DEV f32x4 mfma16(bf16x8 a, bf16x8 b, f32x4 c){
  return __builtin_amdgcn_mfma_f32_16x16x32_bf16(a, b, c, 0, 0, 0);
}
DEV i32x4 mfma_i8(i32x4 a, i32x4 b, i32x4 c){
  return __builtin_amdgcn_mfma_i32_16x16x64_i8(a, b, c, 0, 0, 0);
}

typedef __attribute__((address_space(3))) void lds_vt;
typedef const __attribute__((address_space(1))) void gm_vt;
DEV void gload16(const void* g, void* l){
  __builtin_amdgcn_global_load_lds((gm_vt*)g, (lds_vt*)l, 16, 0, 0);
}

#define LGKM0 asm volatile("s_waitcnt lgkmcnt(0)" ::: "memory")
#define SBAR  __builtin_amdgcn_sched_barrier(0)

// i16 -> (hi,lo) i8 split
DEV void qsplit(float v, signed char& dh, signed char& dl){
  int d16 = (int)rintf(v * 4096.f);
  d16 = d16 < -32512 ? -32512 : (d16 > 32512 ? 32512 : d16);
  int l = ((d16 + 128) & 255) - 128;
  dh = (signed char)((d16 - l) >> 8);
  dl = (signed char)l;
}

// ======== BIG-TILE GEMM v2 (round-7 verified skeleton + intra-tile parity quarters) ========
// 256x256 tile, BK=64; 8 waves (2M x 4N); wave tile 128x64; LDS 128KB 2-dbuf.
// Per tile: vmcnt(0); s_barrier; issue STAGE(t+1); then FOUR quarter-phases
// {reads -> lgkmcnt(0)+sched_barrier -> 16 MFMA}; odd-SIMD waves (w>=4) run the
// kk-halves in opposite order so one wave's MFMA overlaps its SIMD-partner's reads.
// No barrier inside the divergent region (race-free). Staging/reads byte-identical
// to round 7 (refcheck'd). NPAIR=3: split-3 plane pairs. EPI: 0 f32 | 1 split-bf16 | 2 i8-quant.

template<int NPAIR, int EPI>
__global__ __launch_bounds__(512, 2) void gemm_big(
    const unsigned short* __restrict__ A0p, const unsigned short* __restrict__ A1p,
    const unsigned short* __restrict__ B0p, const unsigned short* __restrict__ B1p,
    int lda, int ldb, int MBLK, int NBLK, int nkt,
    size_t a_bs, size_t b_bs,
    float* __restrict__ C, int ldc, size_t c_bs,
    const float* __restrict__ bias,
    unsigned short* __restrict__ oh, unsigned short* __restrict__ ol)
{
  __shared__ char lds[131072];
  const int tid  = threadIdx.x;
  const int w    = tid >> 6;
  const int lane = tid & 63;
  const int wr = w >> 2, wc = w & 3;
  const int lr = lane & 15, lg = lane >> 4;

  const int nwg = gridDim.x;
  const int wg  = (blockIdx.x & 7) * (nwg >> 3) + (blockIdx.x >> 3);
  const int per = MBLK * NBLK;
  const int b   = wg / per;
  const int rr  = wg - b * per;
  const int m0  = (rr / NBLK) * 256;
  const int n0  = (rr % NBLK) * 256;

  const unsigned short* Ab0 = A0p + b * a_bs + (size_t)m0 * lda;
  const unsigned short* Ab1 = A1p + b * a_bs + (size_t)m0 * lda;
  const unsigned short* Bb0 = B0p + b * b_bs + (size_t)n0 * ldb;
  const unsigned short* Bb1 = B1p + b * b_bs + (size_t)n0 * ldb;

  const int NT = nkt * NPAIR;
  const int wu = __builtin_amdgcn_readfirstlane(w);
  const int rg = lane >> 3, sl = lane & 7;

  f32x4 acc[8][4];
#pragma unroll
  for (int m = 0; m < 8; ++m)
#pragma unroll
    for (int n = 0; n < 4; ++n) acc[m][n] = (f32x4){0.f, 0.f, 0.f, 0.f};

  auto STAGE = [&](int t, int bufsel){
    int kp, pr;
    if (NPAIR == 3){ kp = t / 3; pr = t - kp * 3; } else { kp = t; pr = 0; }
    const unsigned short* Ap = ((NPAIR == 3) && pr == 1) ? Ab1 : Ab0;
    const unsigned short* Bp = ((NPAIR == 3) && pr == 2) ? Bb1 : Bb0;
    Ap += kp * 64; Bp += kp * 64;
    char* Abuf = lds + bufsel * 65536;
    char* Bbuf = Abuf + 32768;
#pragma unroll
    for (int j = 0; j < 4; ++j){
      int row = wu * 32 + j * 8 + rg;
      int g = sl ^ swz8(row);
      gload16(Ap + (size_t)row * lda + g * 8, Abuf + (wu * 32 + j * 8) * 128);
      gload16(Bp + (size_t)row * ldb + g * 8, Bbuf + (wu * 32 + j * 8) * 128);
    }
  };

  bf16x8 afr[4], bfr[4];

  auto RDQ = [&](const char* Abuf, const char* Bbuf, int kk, int mh){
    if (mh == 0){
#pragma unroll
      for (int nn = 0; nn < 4; ++nn){
        int row = wc * 64 + nn * 16 + lr;
        int g = (kk * 4 + lg) ^ swz8(row);
        bfr[nn] = *(const bf16x8*)(Bbuf + row * 128 + g * 16);
      }
    }
#pragma unroll
    for (int mm = 0; mm < 4; ++mm){
      int row = wr * 128 + (mh * 4 + mm) * 16 + lr;
      int g = (kk * 4 + lg) ^ swz8(row);
      afr[mm] = *(const bf16x8*)(Abuf + row * 128 + g * 16);
    }
  };
  auto MMQ = [&](int mh){
    __builtin_amdgcn_s_setprio(1);
#pragma unroll
    for (int mm = 0; mm < 4; ++mm)
#pragma unroll
      for (int nn = 0; nn < 4; ++nn)
        acc[mh * 4 + mm][nn] = mfma16(afr[mm], bfr[nn], acc[mh * 4 + mm][nn]);
    __builtin_amdgcn_s_setprio(0);
  };

#define QTR(AB, BB, kk, mh) { RDQ(AB, BB, kk, mh); LGKM0; SBAR; MMQ(mh); SBAR; }

  STAGE(0, 0);

  for (int t = 0; t < NT; ++t){
    asm volatile("s_waitcnt vmcnt(0)" ::: "memory");
    __builtin_amdgcn_s_barrier();
    SBAR;
    if (t + 1 < NT) STAGE(t + 1, (t + 1) & 1);
    SBAR;
    const char* Abuf = lds + (t & 1) * 65536;
    const char* Bbuf = Abuf + 32768;
    if (wu < 4){
      QTR(Abuf, Bbuf, 0, 0) QTR(Abuf, Bbuf, 0, 1)
      QTR(Abuf, Bbuf, 1, 0) QTR(Abuf, Bbuf, 1, 1)
    } else {
      QTR(Abuf, Bbuf, 1, 0) QTR(Abuf, Bbuf, 1, 1)
      QTR(Abuf, Bbuf, 0, 0) QTR(Abuf, Bbuf, 0, 1)
    }
  }
#undef QTR

#pragma unroll
  for (int m = 0; m < 8; ++m){
    int grow = m0 + wr * 128 + m * 16 + lg * 4;
#pragma unroll
    for (int n = 0; n < 4; ++n){
      int gcol = n0 + wc * 64 + n * 16 + lr;
      if (EPI == 0){
#pragma unroll
        for (int j = 0; j < 4; ++j)
          C[b * c_bs + (size_t)(grow + j) * ldc + gcol] = acc[m][n][j];
      } else if (EPI == 1){
        float bv = bias[gcol];
#pragma unroll
        for (int j = 0; j < 4; ++j){
          float v = acc[m][n][j] + bv;
          unsigned short h = f2bf(v);
          size_t idx = (size_t)(grow + j) * ldc + gcol;
          oh[idx] = h;
          ol[idx] = f2bf(v - bf2f(h));
        }
      } else {
        float bv = bias[gcol];
#pragma unroll
        for (int j = 0; j < 4; ++j){
          signed char qh, ql;
          qsplit(acc[m][n][j] + bv, qh, ql);
          size_t idx = (size_t)(grow + j) * ldc + gcol;
          ((signed char*)oh)[idx] = qh;
          ((signed char*)ol)[idx] = ql;
        }
      }
    }
  }
}

// ======== i8 SCORE GEMM v2 (round-12 verified skeleton + parity 3-phase) ========
// Block 256x128; waves 2M x 4N; wave tile 128x32; acc0=hh, acc1=mid (shared).
// Phases: even waves {ah+bh->hh}{bl->hl}{al->lh}; odd waves {al+bh->lh}{ah->hh}{bl->hl}.
// No barriers in divergent region. score = (acc0*2^16 + acc1*2^8)*2^-24.

__global__ __launch_bounds__(512, 2) void score_i8(
    const signed char* __restrict__ dqh, const signed char* __restrict__ dql,
    const signed char* __restrict__ kqh, const signed char* __restrict__ kql,
    float* __restrict__ scores)
{
  __shared__ char lds[98304];
  const int tid  = threadIdx.x;
  const int w    = tid >> 6;
  const int lane = tid & 63;
  const int wr = w >> 2, wc = w & 3;
  const int lr = lane & 15, lg = lane >> 4;

  const int nwg = gridDim.x;
  const int wg  = (blockIdx.x & 7) * (nwg >> 3) + (blockIdx.x >> 3);
  const int b   = wg >> 7;
  const int rr  = wg & 127;
  const int m0  = (rr >> 4) * 256;
  const int n0  = (rr & 15) * 128;

  const signed char* Ah_g = dqh + ((size_t)b * 2048 + m0) * 1024;
  const signed char* Al_g = dql + ((size_t)b * 2048 + m0) * 1024;
  const signed char* Bh_g = kqh + ((size_t)b * 2048 + n0) * 1024;
  const signed char* Bl_g = kql + ((size_t)b * 2048 + n0) * 1024;
  const int wu = __builtin_amdgcn_readfirstlane(w);

  i32x4 acc0[8][2], acc1[8][2];
#pragma unroll
  for (int m = 0; m < 8; ++m)
#pragma unroll
    for (int n = 0; n < 2; ++n){ acc0[m][n] = (i32x4){0,0,0,0}; acc1[m][n] = (i32x4){0,0,0,0}; }

  auto STAGE = [&](int t, int buf){
    int k0 = t * 64;
    char* L = lds + buf * 49152;
    int c = (tid & 3) << 4;
#pragma unroll
    for (int j = 0; j < 2; ++j){
      int row = j * 128 + (tid >> 2);
      gload16(Ah_g + (size_t)row * 1024 + k0 + c, L + j * 8192 + wu * 1024);
      gload16(Al_g + (size_t)row * 1024 + k0 + c, L + 16384 + j * 8192 + wu * 1024);
    }
    {
      int row = tid >> 2;
      gload16(Bh_g + (size_t)row * 1024 + k0 + c, L + 32768 + wu * 1024);
      gload16(Bl_g + (size_t)row * 1024 + k0 + c, L + 40960 + wu * 1024);
    }
  };

  i32x4 ah[8], al[8], bh[2], bl[2];

  auto RD_AH = [&](const char* L){
#pragma unroll
    for (int mm = 0; mm < 8; ++mm){
      int row = wr * 128 + mm * 16 + lr;
      ah[mm] = *(const i32x4*)(L + row * 64 + lg * 16);
    }
  };
  auto RD_AL = [&](const char* L){
#pragma unroll
    for (int mm = 0; mm < 8; ++mm){
      int row = wr * 128 + mm * 16 + lr;
      al[mm] = *(const i32x4*)(L + 16384 + row * 64 + lg * 16);
    }
  };
  auto RD_BH = [&](const char* L){
#pragma unroll
    for (int nn = 0; nn < 2; ++nn){
      int row = wc * 32 + nn * 16 + lr;
      bh[nn] = *(const i32x4*)(L + 32768 + row * 64 + lg * 16);
    }
  };
  auto RD_BL = [&](const char* L){
#pragma unroll
    for (int nn = 0; nn < 2; ++nn){
      int row = wc * 32 + nn * 16 + lr;
      bl[nn] = *(const i32x4*)(L + 40960 + row * 64 + lg * 16);
    }
  };
  auto MM_HH = [&](){
    __builtin_amdgcn_s_setprio(1);
#pragma unroll
    for (int mm = 0; mm < 8; ++mm)
#pragma unroll
      for (int nn = 0; nn < 2; ++nn)
        acc0[mm][nn] = mfma_i8(ah[mm], bh[nn], acc0[mm][nn]);
    __builtin_amdgcn_s_setprio(0);
  };
  auto MM_HL = [&](){
    __builtin_amdgcn_s_setprio(1);
#pragma unroll
    for (int mm = 0; mm < 8; ++mm)
#pragma unroll
      for (int nn = 0; nn < 2; ++nn)
        acc1[mm][nn] = mfma_i8(ah[mm], bl[nn], acc1[mm][nn]);
    __builtin_amdgcn_s_setprio(0);
  };
  auto MM_LH = [&](){
    __builtin_amdgcn_s_setprio(1);
#pragma unroll
    for (int mm = 0; mm < 8; ++mm)
#pragma unroll
      for (int nn = 0; nn < 2; ++nn)
        acc1[mm][nn] = mfma_i8(al[mm], bh[nn], acc1[mm][nn]);
    __builtin_amdgcn_s_setprio(0);
  };

  STAGE(0, 0);

  for (int t = 0; t < 16; ++t){
    asm volatile("s_waitcnt vmcnt(0)" ::: "memory");
    __builtin_amdgcn_s_barrier();
    SBAR;
    if (t + 1 < 16) STAGE(t + 1, (t + 1) & 1);
    SBAR;
    const char* L = lds + (t & 1) * 49152;
    if (wu < 4){
      RD_AH(L); RD_BH(L); LGKM0; SBAR; MM_HH(); SBAR;
      RD_BL(L);           LGKM0; SBAR; MM_HL(); SBAR;
      RD_AL(L);           LGKM0; SBAR; MM_LH(); SBAR;
    } else {
      RD_AL(L); RD_BH(L); LGKM0; SBAR; MM_LH(); SBAR;
      RD_AH(L);           LGKM0; SBAR; MM_HH(); SBAR;
      RD_BL(L);           LGKM0; SBAR; MM_HL(); SBAR;
    }
  }

  const float inv = 5.9604644775390625e-8f;   // 2^-24
#pragma unroll
  for (int mm = 0; mm < 8; ++mm){
    int grow = m0 + wr * 128 + mm * 16 + lg * 4;
#pragma unroll
    for (int nn = 0; nn < 2; ++nn){
      int gcol = n0 + wc * 32 + nn * 16 + lr;
#pragma unroll
      for (int j = 0; j < 4; ++j)
        scores[((size_t)b * 2048 + grow + j) * 2048 + gcol] =
          ((float)acc0[mm][nn][j] * 65536.f + (float)acc1[mm][nn][j] * 256.f) * inv;
    }
  }
}

// ---------------- legacy staging / compute (fallback tiers) ----------------

DEV void stage_raw(char* L, const unsigned short* src, int lda, int tid){
#pragma unroll
  for (int i = 0; i < 4; ++i){
    int chunk = i * 256 + tid;
    int row = chunk >> 3;
    int c8 = (chunk & 7) << 3;
    u32x4 v = *(const u32x4*)(src + (size_t)row * lda + c8);
    *(u32x4*)(L + row * 128 + swzb(row, c8 << 1)) = v;
  }
}

DEV void stage_f32_split(char* Lhi, char* Llo, const float* src, int lda, int tid){
#pragma unroll
  for (int i = 0; i < 8; ++i){
    int chunk = i * 256 + tid;
    int row = chunk >> 4;
    int c4 = (chunk & 15) << 2;
    f32x4 v = *(const f32x4*)(src + (size_t)row * lda + c4);
    unsigned short h0 = f2bf(v[0]), h1 = f2bf(v[1]), h2 = f2bf(v[2]), h3 = f2bf(v[3]);
    u32x2 hw, lw;
    hw[0] = (unsigned)h0 | ((unsigned)h1 << 16); hw[1] = (unsigned)h2 | ((unsigned)h3 << 16);
    lw[0] = (unsigned)f2bf(v[0] - bf2f(h0)) | ((unsigned)f2bf(v[1] - bf2f(h1)) << 16);
    lw[1] = (unsigned)f2bf(v[2] - bf2f(h2)) | ((unsigned)f2bf(v[3] - bf2f(h3)) << 16);
    int off = row * 128 + swzb(row, c4 << 1);
    *(u32x2*)(Lhi + off) = hw;
    *(u32x2*)(Llo + off) = lw;
  }
}

DEV void stage_f32_plain(char* L, const float* src, int lda, int tid){
#pragma unroll
  for (int i = 0; i < 8; ++i){
    int chunk = i * 256 + tid;
    int row = chunk >> 4;
    int c4 = (chunk & 15) << 2;
    f32x4 v = *(const f32x4*)(src + (size_t)row * lda + c4);
    u32x2 hw;
    hw[0] = (unsigned)f2bf(v[0]) | ((unsigned)f2bf(v[1]) << 16);
    hw[1] = (unsigned)f2bf(v[2]) | ((unsigned)f2bf(v[3]) << 16);
    *(u32x2*)(L + row * 128 + swzb(row, c4 << 1)) = hw;
  }
}

DEV void stage_f32_T(char* L, const float* src, int ldb, int tid){
#pragma unroll
  for (int i = 0; i < 8; ++i){
    int mb = i * 256 + tid;
    int np = mb & 63, kp = mb >> 6;
    int gk = kp << 1, gn = np << 1;
    const float* p = src + (size_t)gk * ldb + gn;
    f32x2 r0 = *(const f32x2*)p;
    f32x2 r1 = *(const f32x2*)(p + ldb);
    *(unsigned*)(L + gn * 128 + swzb(gn, gk << 1))           = (unsigned)f2bf(r0[0]) | ((unsigned)f2bf(r1[0]) << 16);
    *(unsigned*)(L + (gn + 1) * 128 + swzb(gn + 1, gk << 1)) = (unsigned)f2bf(r0[1]) | ((unsigned)f2bf(r1[1]) << 16);
  }
}

DEV void compute_split(f32x4 acc[4][4], const char* Ahi, const char* Alo,
                       const char* Bhi, const char* Blo, int wr, int wc, int lane){
  int lr = lane & 15, lg = lane >> 4;
#pragma unroll
  for (int kk = 0; kk < 2; ++kk){
    int cb = kk * 64 + lg * 16;
    bf16x8 ah[4], al[4], bh[4], bl[4];
#pragma unroll
    for (int m = 0; m < 4; ++m){
      int r = wr * 64 + m * 16 + lr;
      ah[m] = *(const bf16x8*)(Ahi + loff(r, cb));
      al[m] = *(const bf16x8*)(Alo + loff(r, cb));
    }
#pragma unroll
    for (int n = 0; n < 4; ++n){
      int r = wc * 64 + n * 16 + lr;
      bh[n] = *(const bf16x8*)(Bhi + loff(r, cb));
      bl[n] = *(const bf16x8*)(Blo + loff(r, cb));
    }
#pragma unroll
    for (int m = 0; m < 4; ++m)
#pragma unroll
      for (int n = 0; n < 4; ++n){
        acc[m][n] = mfma16(ah[m], bh[n], acc[m][n]);
        acc[m][n] = mfma16(al[m], bh[n], acc[m][n]);
        acc[m][n] = mfma16(ah[m], bl[n], acc[m][n]);
      }
  }
}

DEV void compute_plain(f32x4 acc[4][4], const char* A, const char* B, int wr, int wc, int lane){
  int lr = lane & 15, lg = lane >> 4;
#pragma unroll
  for (int kk = 0; kk < 2; ++kk){
    int cb = kk * 64 + lg * 16;
    bf16x8 af[4], bf_[4];
#pragma unroll
    for (int m = 0; m < 4; ++m)
      af[m] = *(const bf16x8*)(A + loff(wr * 64 + m * 16 + lr, cb));
#pragma unroll
    for (int n = 0; n < 4; ++n)
      bf_[n] = *(const bf16x8*)(B + loff(wc * 64 + n * 16 + lr, cb));
#pragma unroll
    for (int m = 0; m < 4; ++m)
#pragma unroll
      for (int n = 0; n < 4; ++n)
        acc[m][n] = mfma16(af[m], bf_[n], acc[m][n]);
  }
}

// ---------------- prep kernels ----------------

template<bool SPLIT>
__global__ __launch_bounds__(256) void transpose_prep(
    const float* __restrict__ in, size_t in_bstride, int in_ld,
    unsigned short* __restrict__ oh, unsigned short* __restrict__ ol,
    size_t out_bstride, int out_ld)
{
  __shared__ float T[64][65];
  const int t = threadIdx.x;
  const int r0 = blockIdx.x * 64, c0 = blockIdx.y * 64;
  const float* src = in + (size_t)blockIdx.z * in_bstride;
#pragma unroll
  for (int i = 0; i < 4; ++i){
    int r = (t >> 4) + i * 16;
    int c = (t & 15) * 4;
    f32x4 v = *(const f32x4*)(src + (size_t)(r0 + r) * in_ld + c0 + c);
#pragma unroll
    for (int j = 0; j < 4; ++j) T[r][c + j] = v[j];
  }
  __syncthreads();
#pragma unroll
  for (int i = 0; i < 4; ++i){
    int c = (t >> 4) + i * 16;
    int r = (t & 15) * 4;
    float v0 = T[r][c], v1 = T[r + 1][c], v2 = T[r + 2][c], v3 = T[r + 3][c];
    unsigned short h0 = f2bf(v0), h1 = f2bf(v1), h2 = f2bf(v2), h3 = f2bf(v3);
    u32x2 hw;
    hw[0] = (unsigned)h0 | ((unsigned)h1 << 16);
    hw[1] = (unsigned)h2 | ((unsigned)h3 << 16);
    size_t off = (size_t)blockIdx.z * out_bstride + (size_t)(c0 + c) * out_ld + r0 + r;
    *(u32x2*)(oh + off) = hw;
    if (SPLIT){
      u32x2 lw;
      lw[0] = (unsigned)f2bf(v0 - bf2f(h0)) | ((unsigned)f2bf(v1 - bf2f(h1)) << 16);
      lw[1] = (unsigned)f2bf(v2 - bf2f(h2)) | ((unsigned)f2bf(v3 - bf2f(h3)) << 16);
      *(u32x2*)(ol + off) = lw;
    }
  }
}

__global__ __launch_bounds__(256) void split_prep(
    const float* __restrict__ in, unsigned short* __restrict__ oh,
    unsigned short* __restrict__ ol)
{
  size_t i = ((size_t)blockIdx.x * 256 + threadIdx.x) * 4;
  f32x4 v = *(const f32x4*)(in + i);
  unsigned short h0 = f2bf(v[0]), h1 = f2bf(v[1]), h2 = f2bf(v[2]), h3 = f2bf(v[3]);
  u32x2 hw, lw;
  hw[0] = (unsigned)h0 | ((unsigned)h1 << 16); hw[1] = (unsigned)h2 | ((unsigned)h3 << 16);
  lw[0] = (unsigned)f2bf(v[0] - bf2f(h0)) | ((unsigned)f2bf(v[1] - bf2f(h1)) << 16);
  lw[1] = (unsigned)f2bf(v[2] - bf2f(h2)) | ((unsigned)f2bf(v[3] - bf2f(h3)) << 16);
  *(u32x2*)(oh + i) = hw;
  *(u32x2*)(ol + i) = lw;
}

__global__ __launch_bounds__(256) void quant_prep(
    const float* __restrict__ in, signed char* __restrict__ oh,
    signed char* __restrict__ ol)
{
  size_t i = ((size_t)blockIdx.x * 256 + threadIdx.x) * 8;
  f32x4 a = *(const f32x4*)(in + i);
  f32x4 c = *(const f32x4*)(in + i + 4);
  unsigned hw0 = 0, hw1 = 0, lw0 = 0, lw1 = 0;
#pragma unroll
  for (int j = 0; j < 4; ++j){
    signed char qh, ql;
    qsplit(a[j], qh, ql);
    hw0 |= ((unsigned)(unsigned char)qh) << (8 * j);
    lw0 |= ((unsigned)(unsigned char)ql) << (8 * j);
    qsplit(c[j], qh, ql);
    hw1 |= ((unsigned)(unsigned char)qh) << (8 * j);
    lw1 |= ((unsigned)(unsigned char)ql) << (8 * j);
  }
  u32x2 hv, lv;
  hv[0] = hw0; hv[1] = hw1; lv[0] = lw0; lv[1] = lw1;
  *(u32x2*)(oh + i) = hv;
  *(u32x2*)(ol + i) = lv;
}

// ---------------- legacy kernels (fallback tiers) ----------------

__global__ __launch_bounds__(256, 2) void keys_gemm(
    const float* __restrict__ enc,
    const unsigned short* __restrict__ WaTh, const unsigned short* __restrict__ WaTl,
    const float* __restrict__ bias,
    unsigned short* __restrict__ khi, unsigned short* __restrict__ klo)
{
  __shared__ char lds[65536];
  char *Ahi = lds, *Alo = lds + 16384, *Bhi = lds + 32768, *Blo = lds + 49152;
  const int tid = threadIdx.x;
  const int lane = tid & 63, w = tid >> 6;
  const int wr = w >> 1, wc = w & 1;
  const int lr = lane & 15, lg = lane >> 4;
  const int m0 = blockIdx.y * 128;
  const int n0 = blockIdx.x * 128;

  f32x4 acc[4][4];
#pragma unroll
  for (int m = 0; m < 4; ++m)
#pragma unroll
    for (int n = 0; n < 4; ++n) acc[m][n] = (f32x4){0.f, 0.f, 0.f, 0.f};

  for (int k0 = 0; k0 < 1024; k0 += 64){
    __syncthreads();
    stage_f32_split(Ahi, Alo, enc + (size_t)m0 * 1024 + k0, 1024, tid);
    stage_raw(Bhi, WaTh + (size_t)n0 * 1024 + k0, 1024, tid);
    stage_raw(Blo, WaTl + (size_t)n0 * 1024 + k0, 1024, tid);
    __syncthreads();
    compute_split(acc, Ahi, Alo, Bhi, Blo, wr, wc, lane);
  }

#pragma unroll
  for (int n = 0; n < 4; ++n){
    int col = n0 + wc * 64 + n * 16 + lr;
    float bv = bias[col];
#pragma unroll
    for (int m = 0; m < 4; ++m){
      int rbase = m0 + wr * 64 + m * 16 + lg * 4;
#pragma unroll
      for (int j = 0; j < 4; ++j){
        float v = acc[m][n][j] + bv;
        unsigned short h = f2bf(v);
        size_t idx = (size_t)(rbase + j) * 1024 + col;
        khi[idx] = h;
        klo[idx] = f2bf(v - bf2f(h));
      }
    }
  }
}

template<bool PRESPLIT>
__global__ __launch_bounds__(256, 2) void score_gemm(
    const float* __restrict__ dec,
    const unsigned short* __restrict__ dech, const unsigned short* __restrict__ decl,
    const unsigned short* __restrict__ khi, const unsigned short* __restrict__ klo,
    float* __restrict__ scores)
{
  __shared__ char lds[65536];
  char *Ahi = lds, *Alo = lds + 16384, *Bhi = lds + 32768, *Blo = lds + 49152;
  const int tid = threadIdx.x;
  const int lane = tid & 63, w = tid >> 6;
  const int wr = w >> 1, wc = w & 1;
  const int lr = lane & 15, lg = lane >> 4;
  const int b  = blockIdx.z;
  const int m0 = blockIdx.y * 128;
  const int n0 = blockIdx.x * 128;

  f32x4 acc[4][4];
#pragma unroll
  for (int m = 0; m < 4; ++m)
#pragma unroll
    for (int n = 0; n < 4; ++n) acc[m][n] = (f32x4){0.f, 0.f, 0.f, 0.f};

  const size_t arow = (size_t)b * 2048 + m0;
  const size_t brow = (size_t)b * 2048 + n0;

  for (int k0 = 0; k0 < 1024; k0 += 64){
    __syncthreads();
    if (PRESPLIT){
      stage_raw(Ahi, dech + arow * 1024 + k0, 1024, tid);
      stage_raw(Alo, decl + arow * 1024 + k0, 1024, tid);
    } else {
      stage_f32_split(Ahi, Alo, dec + arow * 1024 + k0, 1024, tid);
    }
    stage_raw(Bhi, khi + brow * 1024 + k0, 1024, tid);
    stage_raw(Blo, klo + brow * 1024 + k0, 1024, tid);
    __syncthreads();
    compute_split(acc, Ahi, Alo, Bhi, Blo, wr, wc, lane);
  }

#pragma unroll
  for (int n = 0; n < 4; ++n){
    int col = n0 + wc * 64 + n * 16 + lr;
#pragma unroll
    for (int m = 0; m < 4; ++m){
      int rbase = m0 + wr * 64 + m * 16 + lg * 4;
#pragma unroll
      for (int j = 0; j < 4; ++j)
        scores[((size_t)b * 2048 + rbase + j) * 2048 + col] = acc[m][n][j];
    }
  }
}

// ---------------- softmax ----------------

template<bool DUALW>
__global__ __launch_bounds__(256, 4) void softmax_k(float* scores, unsigned short* alignb)
{
  const int row = blockIdx.x;
  const int t = threadIdx.x;
  float* src = scores + (size_t)row * 2048;
  f32x4 va = *(const f32x4*)(src + t * 8);
  f32x4 vb = *(const f32x4*)(src + t * 8 + 4);
  float f[8];
#pragma unroll
  for (int j = 0; j < 4; ++j){ f[j] = va[j]; f[4 + j] = vb[j]; }
  float m = -3.0e38f;
#pragma unroll
  for (int j = 0; j < 8; ++j) m = fmaxf(m, f[j]);
#pragma unroll
  for (int o = 1; o < 64; o <<= 1) m = fmaxf(m, __shfl_xor(m, o));
  __shared__ float red[4];
  const int wid = t >> 6;
  if ((t & 63) == 0) red[wid] = m;
  __syncthreads();
  m = fmaxf(fmaxf(red[0], red[1]), fmaxf(red[2], red[3]));
  float p[8]; float s = 0.f;
#pragma unroll
  for (int j = 0; j < 8; ++j){ p[j] = __expf(f[j] - m); s += p[j]; }
#pragma unroll
  for (int o = 1; o < 64; o <<= 1) s += __shfl_xor(s, o);
  __syncthreads();
  if ((t & 63) == 0) red[wid] = s;
  __syncthreads();
  s = (red[0] + red[1]) + (red[2] + red[3]);
  float inv = 1.0f / s;
  f32x4 oa, ob;
#pragma unroll
  for (int j = 0; j < 4; ++j){ oa[j] = p[j] * inv; ob[j] = p[4 + j] * inv; }
  *(f32x4*)(src + t * 8)     = oa;
  *(f32x4*)(src + t * 8 + 4) = ob;
  if (DUALW){
    u32x4 wv;
#pragma unroll
    for (int j = 0; j < 4; ++j){
      float x0 = (j < 2) ? oa[2 * j] : ob[2 * j - 4];
      float x1 = (j < 2) ? oa[2 * j + 1] : ob[2 * j - 3];
      wv[j] = (unsigned)f2bf(x0) | ((unsigned)f2bf(x1) << 16);
    }
    *(u32x4*)(alignb + (size_t)row * 2048 + t * 8) = wv;
  }
}

// ---------------- legacy ctx kernels (fallback tiers) ----------------

__global__ __launch_bounds__(256, 3) void ctx_gemm_fast(
    const unsigned short* __restrict__ alignb,
    const unsigned short* __restrict__ encT,
    float* __restrict__ ctx)
{
  __shared__ char lds[32768];
  char *A = lds, *B = lds + 16384;
  const int tid = threadIdx.x;
  const int lane = tid & 63, w = tid >> 6;
  const int wr = w >> 1, wc = w & 1;
  const int lr = lane & 15, lg = lane >> 4;
  const int wg = blockIdx.x;
  const int n0 = (wg & 7) * 128;
  const int m0 = ((wg >> 3) & 15) * 128;
  const int b  = wg >> 7;

  const unsigned short* Asrc = alignb + ((size_t)b * 2048 + m0) * 2048;
  const unsigned short* Bsrc = encT   + (size_t)b * 2097152 + (size_t)n0 * 2048;

  f32x4 acc[4][4];
#pragma unroll
  for (int m = 0; m < 4; ++m)
#pragma unroll
    for (int n = 0; n < 4; ++n) acc[m][n] = (f32x4){0.f, 0.f, 0.f, 0.f};

  const int row_ = tid >> 3;
  const int c8_  = (tid & 7) << 3;

  u32x4 ra[4], rb[4];
#pragma unroll
  for (int i = 0; i < 4; ++i){
    int row = row_ + i * 32;
    ra[i] = *(const u32x4*)(Asrc + (size_t)row * 2048 + c8_);
    rb[i] = *(const u32x4*)(Bsrc + (size_t)row * 2048 + c8_);
  }

  for (int t = 0; t < 32; ++t){
    __syncthreads();
#pragma unroll
    for (int i = 0; i < 4; ++i){
      int row = row_ + i * 32;
      int off = row * 128 + swzb(row, c8_ << 1);
      *(u32x4*)(A + off) = ra[i];
      *(u32x4*)(B + off) = rb[i];
    }
    __syncthreads();
    if (t + 1 < 32){
      int k0 = (t + 1) * 64;
#pragma unroll
      for (int i = 0; i < 4; ++i){
        int row = row_ + i * 32;
        ra[i] = *(const u32x4*)(Asrc + (size_t)row * 2048 + k0 + c8_);
        rb[i] = *(const u32x4*)(Bsrc + (size_t)row * 2048 + k0 + c8_);
      }
    }
    compute_plain(acc, A, B, wr, wc, lane);
  }

#pragma unroll
  for (int n = 0; n < 4; ++n){
    int col = n0 + wc * 64 + n * 16 + lr;
#pragma unroll
    for (int m = 0; m < 4; ++m){
      int rbase = m0 + wr * 64 + m * 16 + lg * 4;
#pragma unroll
      for (int j = 0; j < 4; ++j)
        ctx[((size_t)b * 2048 + rbase + j) * 1024 + col] = acc[m][n][j];
    }
  }
}

template<bool TRANS_WS>
__global__ __launch_bounds__(256, 2) void ctx_gemm(
    const float* __restrict__ alignf,
    const float* __restrict__ enc, const unsigned short* __restrict__ encT,
    float* __restrict__ ctx)
{
  __shared__ char lds[32768];
  char *A = lds, *B = lds + 16384;
  const int tid = threadIdx.x;
  const int lane = tid & 63, w = tid >> 6;
  const int wr = w >> 1, wc = w & 1;
  const int lr = lane & 15, lg = lane >> 4;
  const int b  = blockIdx.z;
  const int m0 = blockIdx.y * 128;
  const int n0 = blockIdx.x * 128;

  f32x4 acc[4][4];
#pragma unroll
  for (int m = 0; m < 4; ++m)
#pragma unroll
    for (int n = 0; n < 4; ++n) acc[m][n] = (f32x4){0.f, 0.f, 0.f, 0.f};

  const float* Asrc = alignf + ((size_t)b * 2048 + m0) * 2048;

  for (int k0 = 0; k0 < 2048; k0 += 64){
    __syncthreads();
    stage_f32_plain(A, Asrc + k0, 2048, tid);
    if (TRANS_WS)
      stage_raw(B, encT + (size_t)b * 2097152 + (size_t)n0 * 2048 + k0, 2048, tid);
    else
      stage_f32_T(B, enc + ((size_t)b * 2048 + k0) * 1024 + n0, 1024, tid);
    __syncthreads();
    compute_plain(acc, A, B, wr, wc, lane);
  }

#pragma unroll
  for (int n = 0; n < 4; ++n){
    int col = n0 + wc * 64 + n * 16 + lr;
#pragma unroll
    for (int m = 0; m < 4; ++m){
      int rbase = m0 + wr * 64 + m * 16 + lg * 4;
#pragma unroll
      for (int j = 0; j < 4; ++j)
        ctx[((size_t)b * 2048 + rbase + j) * 1024 + col] = acc[m][n][j];
    }
  }
}

// ---------------- launch (layout identical to round 12) ----------------

extern "C" void kernel_launch(void* const* d_in, const int* in_sizes, int n_in,
                              void* d_out, int out_size, void* d_ws, size_t ws_size,
                              hipStream_t stream) {
  const float* enc  = (const float*)d_in[0];
  const float* dec  = (const float*)d_in[1];
  const float* Wa   = (const float*)d_in[2];
  const float* bias = (const float*)d_in[3];

  float* out    = (float*)d_out;
  float* ctx    = out;
  float* alignf = out + (size_t)8 * 2048 * 1024;
  float* scores = alignf;

  unsigned short* WaTh = (unsigned short*)(alignf + 32505856);
  unsigned short* WaTl = WaTh + (size_t)1024 * 1024;

  unsigned short* ench = (unsigned short*)alignf;
  unsigned short* encl = ench + (size_t)16384 * 1024;

  const size_t NKEY    = (size_t)16384 * 1024;
  const size_t ENCT_B  = NKEY * 2;
  const size_t ALIGNB_B= (size_t)8 * 2048 * 2048 * 2;
  const size_t DECP_B  = NKEY * 2;
  bool has_encT   = ws_size >= ENCT_B;
  bool has_alignb = ws_size >= ENCT_B + ALIGNB_B;
  bool has_decp   = ws_size >= ENCT_B + ALIGNB_B + 2 * DECP_B;

  if (has_decp){
    signed char* dqh = (signed char*)d_ws;
    signed char* dql = dqh + NKEY;
    unsigned short* encT = (unsigned short*)(dql + NKEY);
    unsigned short* alignb = encT + (size_t)8 * 1024 * 2048;

    signed char* kqh = (signed char*)ctx;
    signed char* kql = kqh + NKEY;

    transpose_prep<true><<<dim3(16, 16, 1), 256, 0, stream>>>(
        Wa, 0, 1024, WaTh, WaTl, 0, 1024);
    transpose_prep<false><<<dim3(32, 16, 8), 256, 0, stream>>>(
        enc, (size_t)2048 * 1024, 1024, encT, nullptr, (size_t)1024 * 2048, 2048);
    quant_prep<<<dim3(8192), 256, 0, stream>>>(dec, dqh, dql);
    split_prep<<<dim3(16384), 256, 0, stream>>>(enc, ench, encl);

    gemm_big<3, 2><<<256, 512, 0, stream>>>(
        ench, encl, WaTh, WaTl, 1024, 1024, 64, 4, 16,
        0, 0, nullptr, 1024, 0, bias,
        (unsigned short*)kqh, (unsigned short*)kql);

    score_i8<<<1024, 512, 0, stream>>>(dqh, dql, kqh, kql, scores);

    softmax_k<true><<<dim3(16384), 256, 0, stream>>>(scores, alignb);

    gemm_big<1, 0><<<256, 512, 0, stream>>>(
        alignb, alignb, encT, encT, 2048, 2048, 8, 4, 32,
        (size_t)2048 * 2048, (size_t)1024 * 2048, ctx, 1024, (size_t)2048 * 1024,
        nullptr, nullptr, nullptr);
  } else {
    unsigned short* khi = (unsigned short*)ctx;
    unsigned short* klo = khi + NKEY;
    unsigned short* encT   = (unsigned short*)d_ws;
    unsigned short* alignb = (unsigned short*)((char*)d_ws + ENCT_B);

    transpose_prep<true><<<dim3(16, 16, 1), 256, 0, stream>>>(
        Wa, 0, 1024, WaTh, WaTl, 0, 1024);
    if (has_encT)
      transpose_prep<false><<<dim3(32, 16, 8), 256, 0, stream>>>(
          enc, (size_t)2048 * 1024, 1024, encT, nullptr, (size_t)1024 * 2048, 2048);

    keys_gemm<<<dim3(8, 128), 256, 0, stream>>>(enc, WaTh, WaTl, bias, khi, klo);
    score_gemm<false><<<dim3(16, 16, 8), 256, 0, stream>>>(dec, nullptr, nullptr, khi, klo, scores);

    if (has_alignb){
      softmax_k<true><<<dim3(16384), 256, 0, stream>>>(scores, alignb);
      ctx_gemm_fast<<<dim3(1024), 256, 0, stream>>>(alignb, encT, ctx);
    } else {
      softmax_k<false><<<dim3(16384), 256, 0, stream>>>(scores, nullptr);
      if (has_encT)
        ctx_gemm<true><<<dim3(8, 16, 8), 256, 0, stream>>>(alignf, nullptr, encT, ctx);
      else
        ctx_gemm<false><<<dim3(8, 16, 8), 256, 0, stream>>>(alignf, enc, nullptr, ctx);
    }
  }
}

// Round 14
// 380.036 us; speedup vs baseline: 7.0326x; 7.0326x over previous
//
#include <hip/hip_runtime.h>

typedef __attribute__((ext_vector_type(8))) short bf16x8;
typedef __attribute__((ext_vector_type(4))) float f32x4;
typedef __attribute__((ext_vector_type(2))) float f32x2;
typedef __attribute__((ext_vector_type(4))) unsigned int u32x4;
typedef __attribute__((ext_vector_type(2))) unsigned int u32x2;
typedef __attribute__((ext_vector_type(4))) int i32x4;

#define DEV static __device__ __forceinline__

DEV unsigned short f2bf(float x){
  unsigned u = __float_as_uint(x);
  u += 0x7fffu + ((u >> 16) & 1u);
  return (unsigned short)(u >> 16);
}
DEV float bf2f(unsigned short b){ return __uint_as_float(((unsigned)b) << 16); }

DEV int swz8(int row){ return (row + (row >> 3)) & 7; }
DEV int swzb(int row, int cb){ return cb ^ (swz8(row) << 4); }
DEV int loff(int row, int cb){ return row * 128 + swzb(row, cb); }

DEV f32x4 mfma16(bf16x8 a, bf16x8 b, f32x4 c){
  return __builtin_amdgcn_mfma_f32_16x16x32_bf16(a, b, c, 0, 0, 0);
}
DEV i32x4 mfma_i8(i32x4 a, i32x4 b, i32x4 c){
  return __builtin_amdgcn_mfma_i32_16x16x64_i8(a, b, c, 0, 0, 0);
}

typedef __attribute__((address_space(3))) void lds_vt;
typedef const __attribute__((address_space(1))) void gm_vt;
DEV void gload16(const void* g, void* l){
  __builtin_amdgcn_global_load_lds((gm_vt*)g, (lds_vt*)l, 16, 0, 0);
}

// i16 -> (hi,lo) i8 split
DEV void qsplit(float v, signed char& dh, signed char& dl){
  int d16 = (int)rintf(v * 4096.f);
  d16 = d16 < -32512 ? -32512 : (d16 > 32512 ? 32512 : d16);
  int l = ((d16 + 128) & 255) - 128;
  dh = (signed char)((d16 - l) >> 8);
  dl = (signed char)l;
}

// ============ 8-PHASE PIPELINED bf16 GEMM (round-11/12 verified, byte-identical) ============

template<int NPAIR, int EPI>
__global__ __launch_bounds__(512, 2) void gemm_big(
    const unsigned short* __restrict__ A0p, const unsigned short* __restrict__ A1p,
    const unsigned short* __restrict__ B0p, const unsigned short* __restrict__ B1p,
    int lda, int ldb, int MBLK, int NBLK, int nkt,
    size_t a_bs, size_t b_bs,
    float* __restrict__ C, int ldc, size_t c_bs,
    const float* __restrict__ bias,
    unsigned short* __restrict__ oh, unsigned short* __restrict__ ol)
{
  __shared__ char lds[131072];
  const int tid  = threadIdx.x;
  const int w    = tid >> 6;
  const int lane = tid & 63;
  const int wr = w >> 2, wc = w & 3;
  const int lr = lane & 15, lg = lane >> 4;

  const int nwg = gridDim.x;
  const int wg  = (blockIdx.x & 7) * (nwg >> 3) + (blockIdx.x >> 3);
  const int per = MBLK * NBLK;
  const int b   = wg / per;
  const int rr  = wg - b * per;
  const int m0  = (rr / NBLK) * 256;
  const int n0  = (rr % NBLK) * 256;

  const unsigned short* Ab0 = A0p + b * a_bs + (size_t)m0 * lda;
  const unsigned short* Ab1 = A1p + b * a_bs + (size_t)m0 * lda;
  const unsigned short* Bb0 = B0p + b * b_bs + (size_t)n0 * ldb;
  const unsigned short* Bb1 = B1p + b * b_bs + (size_t)n0 * ldb;

  const int NT = nkt * NPAIR;
  const int NI = NT >> 1;
  const int wu = __builtin_amdgcn_readfirstlane(w);

  f32x4 acc[8][4];
#pragma unroll
  for (int m = 0; m < 8; ++m)
#pragma unroll
    for (int n = 0; n < 4; ++n) acc[m][n] = (f32x4){0.f, 0.f, 0.f, 0.f};

  auto STAGEH = [&](int T, int d, int isB, int kh){
    if (T >= NT) return;
    int kp, pr;
    if (NPAIR == 3){ kp = T / 3; pr = T - kp * 3; } else { kp = T; pr = 0; }
    const unsigned short* P = isB ? (((NPAIR == 3) && pr == 2) ? Bb1 : Bb0)
                                  : (((NPAIR == 3) && pr == 1) ? Ab1 : Ab0);
    const int ld = isB ? ldb : lda;
    P += kp * 64 + kh * 32;
    char* dst = lds + d * 65536 + isB * 32768 + kh * 16384;
#pragma unroll
    for (int j = 0; j < 2; ++j){
      int rbase = wu * 32 + j * 16;
      int row = rbase + (lane >> 2);
      int g = (lane & 3) ^ ((row >> 1) & 3);
      gload16(P + (size_t)row * ld + g * 8, dst + rbase * 64);
    }
  };

  bf16x8 af[4], bf[4];

#define PHASE(d, kk, mh, RB, STG, VM) {                                        \
  const char* Asub = lds + (d) * 65536 + (kk) * 16384;                         \
  const char* Bsub = lds + (d) * 65536 + 32768 + (kk) * 16384;                 \
  _Pragma("unroll") for (int mm = 0; mm < 4; ++mm){                            \
    int row = wr * 128 + ((mh) * 4 + mm) * 16 + lr;                            \
    af[mm] = *(const bf16x8*)(Asub + row * 64 + ((lg ^ ((row >> 1) & 3)) << 4)); } \
  if (RB){ _Pragma("unroll") for (int nn = 0; nn < 4; ++nn){                   \
    int row = wc * 64 + nn * 16 + lr;                                          \
    bf[nn] = *(const bf16x8*)(Bsub + row * 64 + ((lg ^ ((row >> 1) & 3)) << 4)); } } \
  STG;                                                                         \
  __builtin_amdgcn_sched_barrier(0);                                           \
  __builtin_amdgcn_s_barrier();                                                \
  asm volatile("s_waitcnt lgkmcnt(0)" ::: "memory");                           \
  __builtin_amdgcn_sched_barrier(0);                                           \
  __builtin_amdgcn_s_setprio(1);                                               \
  _Pragma("unroll") for (int mm = 0; mm < 4; ++mm)                             \
    _Pragma("unroll") for (int nn = 0; nn < 4; ++nn)                           \
      acc[(mh) * 4 + mm][nn] = mfma16(af[mm], bf[nn], acc[(mh) * 4 + mm][nn]); \
  __builtin_amdgcn_s_setprio(0);                                               \
  if (VM) asm volatile("s_waitcnt vmcnt(8)" ::: "memory");                     \
  __builtin_amdgcn_sched_barrier(0);                                           \
  __builtin_amdgcn_s_barrier();                                                \
}

  STAGEH(0, 0, 0, 0); STAGEH(0, 0, 1, 0);
  STAGEH(0, 0, 0, 1); STAGEH(0, 0, 1, 1);
  STAGEH(1, 1, 0, 0); STAGEH(1, 1, 1, 0);
  asm volatile("s_waitcnt vmcnt(4)" ::: "memory");
  __builtin_amdgcn_s_barrier();

  for (int i = 0; i < NI; ++i){
    const int T0 = 2 * i, T1 = 2 * i + 1;
    PHASE(0, 0, 0, 1, STAGEH(T1,     1, 0, 1), 0)
    PHASE(0, 0, 1, 0, STAGEH(T1,     1, 1, 1), 1)
    PHASE(0, 1, 0, 1, STAGEH(T0 + 2, 0, 0, 0), 0)
    PHASE(0, 1, 1, 0, STAGEH(T0 + 2, 0, 1, 0), 1)
    PHASE(1, 0, 0, 1, STAGEH(T0 + 2, 0, 0, 1), 0)
    PHASE(1, 0, 1, 0, STAGEH(T0 + 2, 0, 1, 1), 1)
    PHASE(1, 1, 0, 1, STAGEH(T1 + 2, 1, 0, 0), 0)
    PHASE(1, 1, 1, 0, STAGEH(T1 + 2, 1, 1, 0), 1)
  }
#undef PHASE

#pragma unroll
  for (int m = 0; m < 8; ++m){
    int grow = m0 + wr * 128 + m * 16 + lg * 4;
#pragma unroll
    for (int n = 0; n < 4; ++n){
      int gcol = n0 + wc * 64 + n * 16 + lr;
      if (EPI == 0){
#pragma unroll
        for (int j = 0; j < 4; ++j)
          C[b * c_bs + (size_t)(grow + j) * ldc + gcol] = acc[m][n][j];
      } else if (EPI == 1){
        float bv = bias[gcol];
#pragma unroll
        for (int j = 0; j < 4; ++j){
          float v = acc[m][n][j] + bv;
          unsigned short h = f2bf(v);
          size_t idx = (size_t)(grow + j) * ldc + gcol;
          oh[idx] = h;
          ol[idx] = f2bf(v - bf2f(h));
        }
      } else {
        float bv = bias[gcol];
#pragma unroll
        for (int j = 0; j < 4; ++j){
          signed char qh, ql;
          qsplit(acc[m][n][j] + bv, qh, ql);
          size_t idx = (size_t)(grow + j) * ldc + gcol;
          ((signed char*)oh)[idx] = qh;
          ((signed char*)ol)[idx] = ql;
        }
      }
    }
  }
}

// ======== i8 SCORE GEMM v3: 128x128 tile, 4 waves, 64KB LDS -> 2 blocks/CU ========
// Cross-block overlap (the only mechanism that has raised MfmaUtil in this session).
// Wave tile 64x64 (2M x 2N waves; M_rep=N_rep=4). 4-granule XOR swizzle on 64B rows
// (round-9-verified staging/read pair) -> conflict-free. Registers ~192 at (256,2).
// 3 passes/chunk: hh -> acc0; ah.bl + al.bh -> acc1. score=(acc0*2^16+acc1*2^8)*2^-24.

__global__ __launch_bounds__(256, 2) void score_i8(
    const signed char* __restrict__ dqh, const signed char* __restrict__ dql,
    const signed char* __restrict__ kqh, const signed char* __restrict__ kql,
    float* __restrict__ scores)
{
  __shared__ char lds[65536];
  const int tid  = threadIdx.x;
  const int w    = tid >> 6;
  const int lane = tid & 63;
  const int wr = w >> 1, wc = w & 1;
  const int lr = lane & 15, lg = lane >> 4;

  const int nwg = gridDim.x;                 // 2048, %8==0
  const int wg  = (blockIdx.x & 7) * (nwg >> 3) + (blockIdx.x >> 3);
  const int b   = wg >> 8;                   // 256 blocks per batch
  const int rr  = wg & 255;
  const int m0  = (rr >> 4) * 128;
  const int n0  = (rr & 15) * 128;

  const signed char* Ah_g = dqh + ((size_t)b * 2048 + m0) * 1024;
  const signed char* Al_g = dql + ((size_t)b * 2048 + m0) * 1024;
  const signed char* Bh_g = kqh + ((size_t)b * 2048 + n0) * 1024;
  const signed char* Bl_g = kql + ((size_t)b * 2048 + n0) * 1024;
  const int wu = __builtin_amdgcn_readfirstlane(w);

  i32x4 acc0[4][4], acc1[4][4];
#pragma unroll
  for (int m = 0; m < 4; ++m)
#pragma unroll
    for (int n = 0; n < 4; ++n){ acc0[m][n] = (i32x4){0,0,0,0}; acc1[m][n] = (i32x4){0,0,0,0}; }

  // Stage one K64 chunk (4 planes x 128 rows x 64 B = 32 KB). Wave w stages rows
  // [w*32, w*32+32) of each plane; dest = plane + wu*2048 + j*1024 (+ lane*16 implicit);
  // source granule pre-swizzled: g = (lane&3) ^ ((row>>1)&3).
  auto STAGE = [&](int t, int buf){
    const int k0 = t * 64;
    char* L = lds + buf * 32768;
#pragma unroll
    for (int j = 0; j < 2; ++j){
      int row = wu * 32 + j * 16 + (lane >> 2);
      int g = (lane & 3) ^ ((row >> 1) & 3);
      size_t src = (size_t)row * 1024 + k0 + g * 16;
      char* d = L + wu * 2048 + j * 1024;
      gload16(Ah_g + src, d);
      gload16(Al_g + src, d + 8192);
      gload16(Bh_g + src, d + 16384);
      gload16(Bl_g + src, d + 24576);
    }
  };

  STAGE(0, 0);

  for (int t = 0; t < 16; ++t){
    asm volatile("s_waitcnt vmcnt(0)" ::: "memory");
    __builtin_amdgcn_s_barrier();
    __builtin_amdgcn_sched_barrier(0);
    if (t + 1 < 16) STAGE(t + 1, (t + 1) & 1);
    __builtin_amdgcn_sched_barrier(0);

    const char* L = lds + (t & 1) * 32768;
    i32x4 ah[4], al[4], bh[4], bl[4];
#pragma unroll
    for (int mm = 0; mm < 4; ++mm){
      int row = wr * 64 + mm * 16 + lr;
      int off = row * 64 + ((lg ^ ((row >> 1) & 3)) << 4);
      ah[mm] = *(const i32x4*)(L + off);
      al[mm] = *(const i32x4*)(L + 8192 + off);
    }
#pragma unroll
    for (int nn = 0; nn < 4; ++nn){
      int row = wc * 64 + nn * 16 + lr;
      int off = row * 64 + ((lg ^ ((row >> 1) & 3)) << 4);
      bh[nn] = *(const i32x4*)(L + 16384 + off);
      bl[nn] = *(const i32x4*)(L + 24576 + off);
    }
    __builtin_amdgcn_s_setprio(1);
#pragma unroll
    for (int mm = 0; mm < 4; ++mm)
#pragma unroll
      for (int nn = 0; nn < 4; ++nn)
        acc0[mm][nn] = mfma_i8(ah[mm], bh[nn], acc0[mm][nn]);
#pragma unroll
    for (int mm = 0; mm < 4; ++mm)
#pragma unroll
      for (int nn = 0; nn < 4; ++nn){
        acc1[mm][nn] = mfma_i8(ah[mm], bl[nn], acc1[mm][nn]);
        acc1[mm][nn] = mfma_i8(al[mm], bh[nn], acc1[mm][nn]);
      }
    __builtin_amdgcn_s_setprio(0);
  }

  const float inv = 5.9604644775390625e-8f;   // 2^-24
#pragma unroll
  for (int mm = 0; mm < 4; ++mm){
    int grow = m0 + wr * 64 + mm * 16 + lg * 4;
#pragma unroll
    for (int nn = 0; nn < 4; ++nn){
      int gcol = n0 + wc * 64 + nn * 16 + lr;
#pragma unroll
      for (int j = 0; j < 4; ++j)
        scores[((size_t)b * 2048 + grow + j) * 2048 + gcol] =
          ((float)acc0[mm][nn][j] * 65536.f + (float)acc1[mm][nn][j] * 256.f) * inv;
    }
  }
}

// ---------------- legacy staging / compute (fallback tiers) ----------------

DEV void stage_raw(char* L, const unsigned short* src, int lda, int tid){
#pragma unroll
  for (int i = 0; i < 4; ++i){
    int chunk = i * 256 + tid;
    int row = chunk >> 3;
    int c8 = (chunk & 7) << 3;
    u32x4 v = *(const u32x4*)(src + (size_t)row * lda + c8);
    *(u32x4*)(L + row * 128 + swzb(row, c8 << 1)) = v;
  }
}

DEV void stage_f32_split(char* Lhi, char* Llo, const float* src, int lda, int tid){
#pragma unroll
  for (int i = 0; i < 8; ++i){
    int chunk = i * 256 + tid;
    int row = chunk >> 4;
    int c4 = (chunk & 15) << 2;
    f32x4 v = *(const f32x4*)(src + (size_t)row * lda + c4);
    unsigned short h0 = f2bf(v[0]), h1 = f2bf(v[1]), h2 = f2bf(v[2]), h3 = f2bf(v[3]);
    u32x2 hw, lw;
    hw[0] = (unsigned)h0 | ((unsigned)h1 << 16); hw[1] = (unsigned)h2 | ((unsigned)h3 << 16);
    lw[0] = (unsigned)f2bf(v[0] - bf2f(h0)) | ((unsigned)f2bf(v[1] - bf2f(h1)) << 16);
    lw[1] = (unsigned)f2bf(v[2] - bf2f(h2)) | ((unsigned)f2bf(v[3] - bf2f(h3)) << 16);
    int off = row * 128 + swzb(row, c4 << 1);
    *(u32x2*)(Lhi + off) = hw;
    *(u32x2*)(Llo + off) = lw;
  }
}

DEV void stage_f32_plain(char* L, const float* src, int lda, int tid){
#pragma unroll
  for (int i = 0; i < 8; ++i){
    int chunk = i * 256 + tid;
    int row = chunk >> 4;
    int c4 = (chunk & 15) << 2;
    f32x4 v = *(const f32x4*)(src + (size_t)row * lda + c4);
    u32x2 hw;
    hw[0] = (unsigned)f2bf(v[0]) | ((unsigned)f2bf(v[1]) << 16);
    hw[1] = (unsigned)f2bf(v[2]) | ((unsigned)f2bf(v[3]) << 16);
    *(u32x2*)(L + row * 128 + swzb(row, c4 << 1)) = hw;
  }
}

DEV void stage_f32_T(char* L, const float* src, int ldb, int tid){
#pragma unroll
  for (int i = 0; i < 8; ++i){
    int mb = i * 256 + tid;
    int np = mb & 63, kp = mb >> 6;
    int gk = kp << 1, gn = np << 1;
    const float* p = src + (size_t)gk * ldb + gn;
    f32x2 r0 = *(const f32x2*)p;
    f32x2 r1 = *(const f32x2*)(p + ldb);
    *(unsigned*)(L + gn * 128 + swzb(gn, gk << 1))           = (unsigned)f2bf(r0[0]) | ((unsigned)f2bf(r1[0]) << 16);
    *(unsigned*)(L + (gn + 1) * 128 + swzb(gn + 1, gk << 1)) = (unsigned)f2bf(r0[1]) | ((unsigned)f2bf(r1[1]) << 16);
  }
}

DEV void compute_split(f32x4 acc[4][4], const char* Ahi, const char* Alo,
                       const char* Bhi, const char* Blo, int wr, int wc, int lane){
  int lr = lane & 15, lg = lane >> 4;
#pragma unroll
  for (int kk = 0; kk < 2; ++kk){
    int cb = kk * 64 + lg * 16;
    bf16x8 ah[4], al[4], bh[4], bl[4];
#pragma unroll
    for (int m = 0; m < 4; ++m){
      int r = wr * 64 + m * 16 + lr;
      ah[m] = *(const bf16x8*)(Ahi + loff(r, cb));
      al[m] = *(const bf16x8*)(Alo + loff(r, cb));
    }
#pragma unroll
    for (int n = 0; n < 4; ++n){
      int r = wc * 64 + n * 16 + lr;
      bh[n] = *(const bf16x8*)(Bhi + loff(r, cb));
      bl[n] = *(const bf16x8*)(Blo + loff(r, cb));
    }
#pragma unroll
    for (int m = 0; m < 4; ++m)
#pragma unroll
      for (int n = 0; n < 4; ++n){
        acc[m][n] = mfma16(ah[m], bh[n], acc[m][n]);
        acc[m][n] = mfma16(al[m], bh[n], acc[m][n]);
        acc[m][n] = mfma16(ah[m], bl[n], acc[m][n]);
      }
  }
}

DEV void compute_plain(f32x4 acc[4][4], const char* A, const char* B, int wr, int wc, int lane){
  int lr = lane & 15, lg = lane >> 4;
#pragma unroll
  for (int kk = 0; kk < 2; ++kk){
    int cb = kk * 64 + lg * 16;
    bf16x8 af[4], bf_[4];
#pragma unroll
    for (int m = 0; m < 4; ++m)
      af[m] = *(const bf16x8*)(A + loff(wr * 64 + m * 16 + lr, cb));
#pragma unroll
    for (int n = 0; n < 4; ++n)
      bf_[n] = *(const bf16x8*)(B + loff(wc * 64 + n * 16 + lr, cb));
#pragma unroll
    for (int m = 0; m < 4; ++m)
#pragma unroll
      for (int n = 0; n < 4; ++n)
        acc[m][n] = mfma16(af[m], bf_[n], acc[m][n]);
  }
}

// ---------------- prep kernels ----------------

// Wa transpose -> bf16 hi/lo planes
template<bool SPLIT>
__global__ __launch_bounds__(256) void transpose_prep(
    const float* __restrict__ in, size_t in_bstride, int in_ld,
    unsigned short* __restrict__ oh, unsigned short* __restrict__ ol,
    size_t out_bstride, int out_ld)
{
  __shared__ float T[64][65];
  const int t = threadIdx.x;
  const int r0 = blockIdx.x * 64, c0 = blockIdx.y * 64;
  const float* src = in + (size_t)blockIdx.z * in_bstride;
#pragma unroll
  for (int i = 0; i < 4; ++i){
    int r = (t >> 4) + i * 16;
    int c = (t & 15) * 4;
    f32x4 v = *(const f32x4*)(src + (size_t)(r0 + r) * in_ld + c0 + c);
#pragma unroll
    for (int j = 0; j < 4; ++j) T[r][c + j] = v[j];
  }
  __syncthreads();
#pragma unroll
  for (int i = 0; i < 4; ++i){
    int c = (t >> 4) + i * 16;
    int r = (t & 15) * 4;
    float v0 = T[r][c], v1 = T[r + 1][c], v2 = T[r + 2][c], v3 = T[r + 3][c];
    unsigned short h0 = f2bf(v0), h1 = f2bf(v1), h2 = f2bf(v2), h3 = f2bf(v3);
    u32x2 hw;
    hw[0] = (unsigned)h0 | ((unsigned)h1 << 16);
    hw[1] = (unsigned)h2 | ((unsigned)h3 << 16);
    size_t off = (size_t)blockIdx.z * out_bstride + (size_t)(c0 + c) * out_ld + r0 + r;
    *(u32x2*)(oh + off) = hw;
    if (SPLIT){
      u32x2 lw;
      lw[0] = (unsigned)f2bf(v0 - bf2f(h0)) | ((unsigned)f2bf(v1 - bf2f(h1)) << 16);
      lw[1] = (unsigned)f2bf(v2 - bf2f(h2)) | ((unsigned)f2bf(v3 - bf2f(h3)) << 16);
      *(u32x2*)(ol + off) = lw;
    }
  }
}

// fused enc prep: one read of enc -> encT (transposed bf16) + ench/encl (split planes)
__global__ __launch_bounds__(256) void enc_prep(
    const float* __restrict__ enc,
    unsigned short* __restrict__ encT,
    unsigned short* __restrict__ ench, unsigned short* __restrict__ encl)
{
  __shared__ float T[64][65];
  const int t = threadIdx.x;
  const int r0 = blockIdx.x * 64, c0 = blockIdx.y * 64;   // r in 2048, c in 1024
  const int b  = blockIdx.z;
  const float* src = enc + (size_t)b * 2048 * 1024;
#pragma unroll
  for (int i = 0; i < 4; ++i){
    int r = (t >> 4) + i * 16;
    int c = (t & 15) * 4;
    f32x4 v = *(const f32x4*)(src + (size_t)(r0 + r) * 1024 + c0 + c);
#pragma unroll
    for (int j = 0; j < 4; ++j) T[r][c + j] = v[j];
    // split planes (row-major, same coords)
    unsigned short h0 = f2bf(v[0]), h1 = f2bf(v[1]), h2 = f2bf(v[2]), h3 = f2bf(v[3]);
    u32x2 hw, lw;
    hw[0] = (unsigned)h0 | ((unsigned)h1 << 16); hw[1] = (unsigned)h2 | ((unsigned)h3 << 16);
    lw[0] = (unsigned)f2bf(v[0] - bf2f(h0)) | ((unsigned)f2bf(v[1] - bf2f(h1)) << 16);
    lw[1] = (unsigned)f2bf(v[2] - bf2f(h2)) | ((unsigned)f2bf(v[3] - bf2f(h3)) << 16);
    size_t roff = ((size_t)b * 2048 + r0 + r) * 1024 + c0 + c;
    *(u32x2*)(ench + roff) = hw;
    *(u32x2*)(encl + roff) = lw;
  }
  __syncthreads();
#pragma unroll
  for (int i = 0; i < 4; ++i){
    int c = (t >> 4) + i * 16;
    int r = (t & 15) * 4;
    u32x2 hw;
    hw[0] = (unsigned)f2bf(T[r][c])     | ((unsigned)f2bf(T[r + 1][c]) << 16);
    hw[1] = (unsigned)f2bf(T[r + 2][c]) | ((unsigned)f2bf(T[r + 3][c]) << 16);
    *(u32x2*)(encT + (size_t)b * 2097152 + (size_t)(c0 + c) * 2048 + r0 + r) = hw;
  }
}

__global__ __launch_bounds__(256) void quant_prep(
    const float* __restrict__ in, signed char* __restrict__ oh,
    signed char* __restrict__ ol)
{
  size_t i = ((size_t)blockIdx.x * 256 + threadIdx.x) * 8;
  f32x4 a = *(const f32x4*)(in + i);
  f32x4 c = *(const f32x4*)(in + i + 4);
  unsigned hw0 = 0, hw1 = 0, lw0 = 0, lw1 = 0;
#pragma unroll
  for (int j = 0; j < 4; ++j){
    signed char qh, ql;
    qsplit(a[j], qh, ql);
    hw0 |= ((unsigned)(unsigned char)qh) << (8 * j);
    lw0 |= ((unsigned)(unsigned char)ql) << (8 * j);
    qsplit(c[j], qh, ql);
    hw1 |= ((unsigned)(unsigned char)qh) << (8 * j);
    lw1 |= ((unsigned)(unsigned char)ql) << (8 * j);
  }
  u32x2 hv, lv;
  hv[0] = hw0; hv[1] = hw1; lv[0] = lw0; lv[1] = lw1;
  *(u32x2*)(oh + i) = hv;
  *(u32x2*)(ol + i) = lv;
}

// ---------------- legacy kernels (fallback tiers) ----------------

__global__ __launch_bounds__(256, 2) void keys_gemm(
    const float* __restrict__ enc,
    const unsigned short* __restrict__ WaTh, const unsigned short* __restrict__ WaTl,
    const float* __restrict__ bias,
    unsigned short* __restrict__ khi, unsigned short* __restrict__ klo)
{
  __shared__ char lds[65536];
  char *Ahi = lds, *Alo = lds + 16384, *Bhi = lds + 32768, *Blo = lds + 49152;
  const int tid = threadIdx.x;
  const int lane = tid & 63, w = tid >> 6;
  const int wr = w >> 1, wc = w & 1;
  const int lr = lane & 15, lg = lane >> 4;
  const int m0 = blockIdx.y * 128;
  const int n0 = blockIdx.x * 128;

  f32x4 acc[4][4];
#pragma unroll
  for (int m = 0; m < 4; ++m)
#pragma unroll
    for (int n = 0; n < 4; ++n) acc[m][n] = (f32x4){0.f, 0.f, 0.f, 0.f};

  for (int k0 = 0; k0 < 1024; k0 += 64){
    __syncthreads();
    stage_f32_split(Ahi, Alo, enc + (size_t)m0 * 1024 + k0, 1024, tid);
    stage_raw(Bhi, WaTh + (size_t)n0 * 1024 + k0, 1024, tid);
    stage_raw(Blo, WaTl + (size_t)n0 * 1024 + k0, 1024, tid);
    __syncthreads();
    compute_split(acc, Ahi, Alo, Bhi, Blo, wr, wc, lane);
  }

#pragma unroll
  for (int n = 0; n < 4; ++n){
    int col = n0 + wc * 64 + n * 16 + lr;
    float bv = bias[col];
#pragma unroll
    for (int m = 0; m < 4; ++m){
      int rbase = m0 + wr * 64 + m * 16 + lg * 4;
#pragma unroll
      for (int j = 0; j < 4; ++j){
        float v = acc[m][n][j] + bv;
        unsigned short h = f2bf(v);
        size_t idx = (size_t)(rbase + j) * 1024 + col;
        khi[idx] = h;
        klo[idx] = f2bf(v - bf2f(h));
      }
    }
  }
}

template<bool PRESPLIT>
__global__ __launch_bounds__(256, 2) void score_gemm(
    const float* __restrict__ dec,
    const unsigned short* __restrict__ dech, const unsigned short* __restrict__ decl,
    const unsigned short* __restrict__ khi, const unsigned short* __restrict__ klo,
    float* __restrict__ scores)
{
  __shared__ char lds[65536];
  char *Ahi = lds, *Alo = lds + 16384, *Bhi = lds + 32768, *Blo = lds + 49152;
  const int tid = threadIdx.x;
  const int lane = tid & 63, w = tid >> 6;
  const int wr = w >> 1, wc = w & 1;
  const int lr = lane & 15, lg = lane >> 4;
  const int b  = blockIdx.z;
  const int m0 = blockIdx.y * 128;
  const int n0 = blockIdx.x * 128;

  f32x4 acc[4][4];
#pragma unroll
  for (int m = 0; m < 4; ++m)
#pragma unroll
    for (int n = 0; n < 4; ++n) acc[m][n] = (f32x4){0.f, 0.f, 0.f, 0.f};

  const size_t arow = (size_t)b * 2048 + m0;
  const size_t brow = (size_t)b * 2048 + n0;

  for (int k0 = 0; k0 < 1024; k0 += 64){
    __syncthreads();
    if (PRESPLIT){
      stage_raw(Ahi, dech + arow * 1024 + k0, 1024, tid);
      stage_raw(Alo, decl + arow * 1024 + k0, 1024, tid);
    } else {
      stage_f32_split(Ahi, Alo, dec + arow * 1024 + k0, 1024, tid);
    }
    stage_raw(Bhi, khi + brow * 1024 + k0, 1024, tid);
    stage_raw(Blo, klo + brow * 1024 + k0, 1024, tid);
    __syncthreads();
    compute_split(acc, Ahi, Alo, Bhi, Blo, wr, wc, lane);
  }

#pragma unroll
  for (int n = 0; n < 4; ++n){
    int col = n0 + wc * 64 + n * 16 + lr;
#pragma unroll
    for (int m = 0; m < 4; ++m){
      int rbase = m0 + wr * 64 + m * 16 + lg * 4;
#pragma unroll
      for (int j = 0; j < 4; ++j)
        scores[((size_t)b * 2048 + rbase + j) * 2048 + col] = acc[m][n][j];
    }
  }
}

// ---------------- softmax ----------------

template<bool DUALW>
__global__ __launch_bounds__(256, 4) void softmax_k(float* scores, unsigned short* alignb)
{
  const int row = blockIdx.x;
  const int t = threadIdx.x;
  float* src = scores + (size_t)row * 2048;
  f32x4 va = *(const f32x4*)(src + t * 8);
  f32x4 vb = *(const f32x4*)(src + t * 8 + 4);
  float f[8];
#pragma unroll
  for (int j = 0; j < 4; ++j){ f[j] = va[j]; f[4 + j] = vb[j]; }
  float m = -3.0e38f;
#pragma unroll
  for (int j = 0; j < 8; ++j) m = fmaxf(m, f[j]);
#pragma unroll
  for (int o = 1; o < 64; o <<= 1) m = fmaxf(m, __shfl_xor(m, o));
  __shared__ float red[4];
  const int wid = t >> 6;
  if ((t & 63) == 0) red[wid] = m;
  __syncthreads();
  m = fmaxf(fmaxf(red[0], red[1]), fmaxf(red[2], red[3]));
  float p[8]; float s = 0.f;
#pragma unroll
  for (int j = 0; j < 8; ++j){ p[j] = __expf(f[j] - m); s += p[j]; }
#pragma unroll
  for (int o = 1; o < 64; o <<= 1) s += __shfl_xor(s, o);
  __syncthreads();
  if ((t & 63) == 0) red[wid] = s;
  __syncthreads();
  s = (red[0] + red[1]) + (red[2] + red[3]);
  float inv = 1.0f / s;
  f32x4 oa, ob;
#pragma unroll
  for (int j = 0; j < 4; ++j){ oa[j] = p[j] * inv; ob[j] = p[4 + j] * inv; }
  *(f32x4*)(src + t * 8)     = oa;
  *(f32x4*)(src + t * 8 + 4) = ob;
  if (DUALW){
    u32x4 wv;
#pragma unroll
    for (int j = 0; j < 4; ++j){
      float x0 = (j < 2) ? oa[2 * j] : ob[2 * j - 4];
      float x1 = (j < 2) ? oa[2 * j + 1] : ob[2 * j - 3];
      wv[j] = (unsigned)f2bf(x0) | ((unsigned)f2bf(x1) << 16);
    }
    *(u32x4*)(alignb + (size_t)row * 2048 + t * 8) = wv;
  }
}

// ---------------- legacy ctx kernels (fallback tiers) ----------------

__global__ __launch_bounds__(256, 3) void ctx_gemm_fast(
    const unsigned short* __restrict__ alignb,
    const unsigned short* __restrict__ encT,
    float* __restrict__ ctx)
{
  __shared__ char lds[32768];
  char *A = lds, *B = lds + 16384;
  const int tid = threadIdx.x;
  const int lane = tid & 63, w = tid >> 6;
  const int wr = w >> 1, wc = w & 1;
  const int lr = lane & 15, lg = lane >> 4;
  const int wg = blockIdx.x;
  const int n0 = (wg & 7) * 128;
  const int m0 = ((wg >> 3) & 15) * 128;
  const int b  = wg >> 7;

  const unsigned short* Asrc = alignb + ((size_t)b * 2048 + m0) * 2048;
  const unsigned short* Bsrc = encT   + (size_t)b * 2097152 + (size_t)n0 * 2048;

  f32x4 acc[4][4];
#pragma unroll
  for (int m = 0; m < 4; ++m)
#pragma unroll
    for (int n = 0; n < 4; ++n) acc[m][n] = (f32x4){0.f, 0.f, 0.f, 0.f};

  const int row_ = tid >> 3;
  const int c8_  = (tid & 7) << 3;

  u32x4 ra[4], rb[4];
#pragma unroll
  for (int i = 0; i < 4; ++i){
    int row = row_ + i * 32;
    ra[i] = *(const u32x4*)(Asrc + (size_t)row * 2048 + c8_);
    rb[i] = *(const u32x4*)(Bsrc + (size_t)row * 2048 + c8_);
  }

  for (int t = 0; t < 32; ++t){
    __syncthreads();
#pragma unroll
    for (int i = 0; i < 4; ++i){
      int row = row_ + i * 32;
      int off = row * 128 + swzb(row, c8_ << 1);
      *(u32x4*)(A + off) = ra[i];
      *(u32x4*)(B + off) = rb[i];
    }
    __syncthreads();
    if (t + 1 < 32){
      int k0 = (t + 1) * 64;
#pragma unroll
      for (int i = 0; i < 4; ++i){
        int row = row_ + i * 32;
        ra[i] = *(const u32x4*)(Asrc + (size_t)row * 2048 + k0 + c8_);
        rb[i] = *(const u32x4*)(Bsrc + (size_t)row * 2048 + k0 + c8_);
      }
    }
    compute_plain(acc, A, B, wr, wc, lane);
  }

#pragma unroll
  for (int n = 0; n < 4; ++n){
    int col = n0 + wc * 64 + n * 16 + lr;
#pragma unroll
    for (int m = 0; m < 4; ++m){
      int rbase = m0 + wr * 64 + m * 16 + lg * 4;
#pragma unroll
      for (int j = 0; j < 4; ++j)
        ctx[((size_t)b * 2048 + rbase + j) * 1024 + col] = acc[m][n][j];
    }
  }
}

template<bool TRANS_WS>
__global__ __launch_bounds__(256, 2) void ctx_gemm(
    const float* __restrict__ alignf,
    const float* __restrict__ enc, const unsigned short* __restrict__ encT,
    float* __restrict__ ctx)
{
  __shared__ char lds[32768];
  char *A = lds, *B = lds + 16384;
  const int tid = threadIdx.x;
  const int lane = tid & 63, w = tid >> 6;
  const int wr = w >> 1, wc = w & 1;
  const int lr = lane & 15, lg = lane >> 4;
  const int b  = blockIdx.z;
  const int m0 = blockIdx.y * 128;
  const int n0 = blockIdx.x * 128;

  f32x4 acc[4][4];
#pragma unroll
  for (int m = 0; m < 4; ++m)
#pragma unroll
    for (int n = 0; n < 4; ++n) acc[m][n] = (f32x4){0.f, 0.f, 0.f, 0.f};

  const float* Asrc = alignf + ((size_t)b * 2048 + m0) * 2048;

  for (int k0 = 0; k0 < 2048; k0 += 64){
    __syncthreads();
    stage_f32_plain(A, Asrc + k0, 2048, tid);
    if (TRANS_WS)
      stage_raw(B, encT + (size_t)b * 2097152 + (size_t)n0 * 2048 + k0, 2048, tid);
    else
      stage_f32_T(B, enc + ((size_t)b * 2048 + k0) * 1024 + n0, 1024, tid);
    __syncthreads();
    compute_plain(acc, A, B, wr, wc, lane);
  }

#pragma unroll
  for (int n = 0; n < 4; ++n){
    int col = n0 + wc * 64 + n * 16 + lr;
#pragma unroll
    for (int m = 0; m < 4; ++m){
      int rbase = m0 + wr * 64 + m * 16 + lg * 4;
#pragma unroll
      for (int j = 0; j < 4; ++j)
        ctx[((size_t)b * 2048 + rbase + j) * 1024 + col] = acc[m][n][j];
    }
  }
}

// ---------------- launch (round-12 layout; enc prep fused) ----------------

extern "C" void kernel_launch(void* const* d_in, const int* in_sizes, int n_in,
                              void* d_out, int out_size, void* d_ws, size_t ws_size,
                              hipStream_t stream) {
  const float* enc  = (const float*)d_in[0];
  const float* dec  = (const float*)d_in[1];
  const float* Wa   = (const float*)d_in[2];
  const float* bias = (const float*)d_in[3];

  float* out    = (float*)d_out;
  float* ctx    = out;
  float* alignf = out + (size_t)8 * 2048 * 1024;
  float* scores = alignf;

  unsigned short* WaTh = (unsigned short*)(alignf + 32505856);
  unsigned short* WaTl = WaTh + (size_t)1024 * 1024;

  unsigned short* ench = (unsigned short*)alignf;
  unsigned short* encl = ench + (size_t)16384 * 1024;

  const size_t NKEY    = (size_t)16384 * 1024;
  const size_t ENCT_B  = NKEY * 2;
  const size_t ALIGNB_B= (size_t)8 * 2048 * 2048 * 2;
  const size_t DECP_B  = NKEY * 2;
  bool has_encT   = ws_size >= ENCT_B;
  bool has_alignb = ws_size >= ENCT_B + ALIGNB_B;
  bool has_decp   = ws_size >= ENCT_B + ALIGNB_B + 2 * DECP_B;

  if (has_decp){
    signed char* dqh = (signed char*)d_ws;
    signed char* dql = dqh + NKEY;
    unsigned short* encT = (unsigned short*)(dql + NKEY);
    unsigned short* alignb = encT + (size_t)8 * 1024 * 2048;

    signed char* kqh = (signed char*)ctx;
    signed char* kql = kqh + NKEY;

    transpose_prep<true><<<dim3(16, 16, 1), 256, 0, stream>>>(
        Wa, 0, 1024, WaTh, WaTl, 0, 1024);
    enc_prep<<<dim3(32, 16, 8), 256, 0, stream>>>(enc, encT, ench, encl);
    quant_prep<<<dim3(8192), 256, 0, stream>>>(dec, dqh, dql);

    gemm_big<3, 2><<<256, 512, 0, stream>>>(
        ench, encl, WaTh, WaTl, 1024, 1024, 64, 4, 16,
        0, 0, nullptr, 1024, 0, bias,
        (unsigned short*)kqh, (unsigned short*)kql);

    score_i8<<<2048, 256, 0, stream>>>(dqh, dql, kqh, kql, scores);

    softmax_k<true><<<dim3(16384), 256, 0, stream>>>(scores, alignb);

    gemm_big<1, 0><<<256, 512, 0, stream>>>(
        alignb, alignb, encT, encT, 2048, 2048, 8, 4, 32,
        (size_t)2048 * 2048, (size_t)1024 * 2048, ctx, 1024, (size_t)2048 * 1024,
        nullptr, nullptr, nullptr);
  } else {
    unsigned short* khi = (unsigned short*)ctx;
    unsigned short* klo = khi + NKEY;
    unsigned short* encT   = (unsigned short*)d_ws;
    unsigned short* alignb = (unsigned short*)((char*)d_ws + ENCT_B);

    transpose_prep<true><<<dim3(16, 16, 1), 256, 0, stream>>>(
        Wa, 0, 1024, WaTh, WaTl, 0, 1024);
    if (has_encT)
      enc_prep<<<dim3(32, 16, 8), 256, 0, stream>>>(enc, encT, ench, encl);

    keys_gemm<<<dim3(8, 128), 256, 0, stream>>>(enc, WaTh, WaTl, bias, khi, klo);
    score_gemm<false><<<dim3(16, 16, 8), 256, 0, stream>>>(dec, nullptr, nullptr, khi, klo, scores);

    if (has_alignb){
      softmax_k<true><<<dim3(16384), 256, 0, stream>>>(scores, alignb);
      ctx_gemm_fast<<<dim3(1024), 256, 0, stream>>>(alignb, encT, ctx);
    } else {
      softmax_k<false><<<dim3(16384), 256, 0, stream>>>(scores, nullptr);
      if (has_encT)
        ctx_gemm<true><<<dim3(8, 16, 8), 256, 0, stream>>>(alignf, nullptr, encT, ctx);
      else
        ctx_gemm<false><<<dim3(8, 16, 8), 256, 0, stream>>>(alignf, enc, nullptr, ctx);
    }
  }
}

// Round 15
// 339.736 us; speedup vs baseline: 7.8668x; 1.1186x over previous
//
#include <hip/hip_runtime.h>

typedef __attribute__((ext_vector_type(8))) short bf16x8;
typedef __attribute__((ext_vector_type(4))) float f32x4;
typedef __attribute__((ext_vector_type(2))) float f32x2;
typedef __attribute__((ext_vector_type(4))) unsigned int u32x4;
typedef __attribute__((ext_vector_type(2))) unsigned int u32x2;
typedef __attribute__((ext_vector_type(4))) int i32x4;

#define DEV static __device__ __forceinline__

DEV unsigned short f2bf(float x){
  unsigned u = __float_as_uint(x);
  u += 0x7fffu + ((u >> 16) & 1u);
  return (unsigned short)(u >> 16);
}
DEV float bf2f(unsigned short b){ return __uint_as_float(((unsigned)b) << 16); }

DEV int swz8(int row){ return (row + (row >> 3)) & 7; }
DEV int swzb(int row, int cb){ return cb ^ (swz8(row) << 4); }
DEV int loff(int row, int cb){ return row * 128 + swzb(row, cb); }

DEV f32x4 mfma16(bf16x8 a, bf16x8 b, f32x4 c){
  return __builtin_amdgcn_mfma_f32_16x16x32_bf16(a, b, c, 0, 0, 0);
}
DEV i32x4 mfma_i8(i32x4 a, i32x4 b, i32x4 c){
  return __builtin_amdgcn_mfma_i32_16x16x64_i8(a, b, c, 0, 0, 0);
}

typedef __attribute__((address_space(3))) void lds_vt;
typedef const __attribute__((address_space(1))) void gm_vt;
DEV void gload16(const void* g, void* l){
  __builtin_amdgcn_global_load_lds((gm_vt*)g, (lds_vt*)l, 16, 0, 0);
}

// i16 -> (hi,lo) i8 split at parametric scale
DEV void qsplitS(float v, float scale, signed char& dh, signed char& dl){
  int d16 = (int)rintf(v * scale);
  d16 = d16 < -32512 ? -32512 : (d16 > 32512 ? 32512 : d16);
  int l = ((d16 + 128) & 255) - 128;
  dh = (signed char)((d16 - l) >> 8);
  dl = (signed char)l;
}
DEV void qsplit(float v, signed char& dh, signed char& dl){ qsplitS(v, 4096.f, dh, dl); }

// ============ 8-PHASE PIPELINED bf16 GEMM (rounds 11-14 verified, byte-identical) ============

template<int NPAIR, int EPI>
__global__ __launch_bounds__(512, 2) void gemm_big(
    const unsigned short* __restrict__ A0p, const unsigned short* __restrict__ A1p,
    const unsigned short* __restrict__ B0p, const unsigned short* __restrict__ B1p,
    int lda, int ldb, int MBLK, int NBLK, int nkt,
    size_t a_bs, size_t b_bs,
    float* __restrict__ C, int ldc, size_t c_bs,
    const float* __restrict__ bias,
    unsigned short* __restrict__ oh, unsigned short* __restrict__ ol)
{
  __shared__ char lds[131072];
  const int tid  = threadIdx.x;
  const int w    = tid >> 6;
  const int lane = tid & 63;
  const int wr = w >> 2, wc = w & 3;
  const int lr = lane & 15, lg = lane >> 4;

  const int nwg = gridDim.x;
  const int wg  = (blockIdx.x & 7) * (nwg >> 3) + (blockIdx.x >> 3);
  const int per = MBLK * NBLK;
  const int b   = wg / per;
  const int rr  = wg - b * per;
  const int m0  = (rr / NBLK) * 256;
  const int n0  = (rr % NBLK) * 256;

  const unsigned short* Ab0 = A0p + b * a_bs + (size_t)m0 * lda;
  const unsigned short* Ab1 = A1p + b * a_bs + (size_t)m0 * lda;
  const unsigned short* Bb0 = B0p + b * b_bs + (size_t)n0 * ldb;
  const unsigned short* Bb1 = B1p + b * b_bs + (size_t)n0 * ldb;

  const int NT = nkt * NPAIR;
  const int NI = NT >> 1;
  const int wu = __builtin_amdgcn_readfirstlane(w);

  f32x4 acc[8][4];
#pragma unroll
  for (int m = 0; m < 8; ++m)
#pragma unroll
    for (int n = 0; n < 4; ++n) acc[m][n] = (f32x4){0.f, 0.f, 0.f, 0.f};

  auto STAGEH = [&](int T, int d, int isB, int kh){
    if (T >= NT) return;
    int kp, pr;
    if (NPAIR == 3){ kp = T / 3; pr = T - kp * 3; } else { kp = T; pr = 0; }
    const unsigned short* P = isB ? (((NPAIR == 3) && pr == 2) ? Bb1 : Bb0)
                                  : (((NPAIR == 3) && pr == 1) ? Ab1 : Ab0);
    const int ld = isB ? ldb : lda;
    P += kp * 64 + kh * 32;
    char* dst = lds + d * 65536 + isB * 32768 + kh * 16384;
#pragma unroll
    for (int j = 0; j < 2; ++j){
      int rbase = wu * 32 + j * 16;
      int row = rbase + (lane >> 2);
      int g = (lane & 3) ^ ((row >> 1) & 3);
      gload16(P + (size_t)row * ld + g * 8, dst + rbase * 64);
    }
  };

  bf16x8 af[4], bf[4];

#define PHASE(d, kk, mh, RB, STG, VM) {                                        \
  const char* Asub = lds + (d) * 65536 + (kk) * 16384;                         \
  const char* Bsub = lds + (d) * 65536 + 32768 + (kk) * 16384;                 \
  _Pragma("unroll") for (int mm = 0; mm < 4; ++mm){                            \
    int row = wr * 128 + ((mh) * 4 + mm) * 16 + lr;                            \
    af[mm] = *(const bf16x8*)(Asub + row * 64 + ((lg ^ ((row >> 1) & 3)) << 4)); } \
  if (RB){ _Pragma("unroll") for (int nn = 0; nn < 4; ++nn){                   \
    int row = wc * 64 + nn * 16 + lr;                                          \
    bf[nn] = *(const bf16x8*)(Bsub + row * 64 + ((lg ^ ((row >> 1) & 3)) << 4)); } } \
  STG;                                                                         \
  __builtin_amdgcn_sched_barrier(0);                                           \
  __builtin_amdgcn_s_barrier();                                                \
  asm volatile("s_waitcnt lgkmcnt(0)" ::: "memory");                           \
  __builtin_amdgcn_sched_barrier(0);                                           \
  __builtin_amdgcn_s_setprio(1);                                               \
  _Pragma("unroll") for (int mm = 0; mm < 4; ++mm)                             \
    _Pragma("unroll") for (int nn = 0; nn < 4; ++nn)                           \
      acc[(mh) * 4 + mm][nn] = mfma16(af[mm], bf[nn], acc[(mh) * 4 + mm][nn]); \
  __builtin_amdgcn_s_setprio(0);                                               \
  if (VM) asm volatile("s_waitcnt vmcnt(8)" ::: "memory");                     \
  __builtin_amdgcn_sched_barrier(0);                                           \
  __builtin_amdgcn_s_barrier();                                                \
}

  STAGEH(0, 0, 0, 0); STAGEH(0, 0, 1, 0);
  STAGEH(0, 0, 0, 1); STAGEH(0, 0, 1, 1);
  STAGEH(1, 1, 0, 0); STAGEH(1, 1, 1, 0);
  asm volatile("s_waitcnt vmcnt(4)" ::: "memory");
  __builtin_amdgcn_s_barrier();

  for (int i = 0; i < NI; ++i){
    const int T0 = 2 * i, T1 = 2 * i + 1;
    PHASE(0, 0, 0, 1, STAGEH(T1,     1, 0, 1), 0)
    PHASE(0, 0, 1, 0, STAGEH(T1,     1, 1, 1), 1)
    PHASE(0, 1, 0, 1, STAGEH(T0 + 2, 0, 0, 0), 0)
    PHASE(0, 1, 1, 0, STAGEH(T0 + 2, 0, 1, 0), 1)
    PHASE(1, 0, 0, 1, STAGEH(T0 + 2, 0, 0, 1), 0)
    PHASE(1, 0, 1, 0, STAGEH(T0 + 2, 0, 1, 1), 1)
    PHASE(1, 1, 0, 1, STAGEH(T1 + 2, 1, 0, 0), 0)
    PHASE(1, 1, 1, 0, STAGEH(T1 + 2, 1, 1, 0), 1)
  }
#undef PHASE

#pragma unroll
  for (int m = 0; m < 8; ++m){
    int grow = m0 + wr * 128 + m * 16 + lg * 4;
#pragma unroll
    for (int n = 0; n < 4; ++n){
      int gcol = n0 + wc * 64 + n * 16 + lr;
      if (EPI == 0){
#pragma unroll
        for (int j = 0; j < 4; ++j)
          C[b * c_bs + (size_t)(grow + j) * ldc + gcol] = acc[m][n][j];
      } else if (EPI == 1){
        float bv = bias[gcol];
#pragma unroll
        for (int j = 0; j < 4; ++j){
          float v = acc[m][n][j] + bv;
          unsigned short h = f2bf(v);
          size_t idx = (size_t)(grow + j) * ldc + gcol;
          oh[idx] = h;
          ol[idx] = f2bf(v - bf2f(h));
        }
      } else {
        float bv = bias[gcol];
#pragma unroll
        for (int j = 0; j < 4; ++j){
          signed char qh, ql;
          qsplit(acc[m][n][j] + bv, qh, ql);
          size_t idx = (size_t)(grow + j) * ldc + gcol;
          ((signed char*)oh)[idx] = qh;
          ((signed char*)ol)[idx] = ql;
        }
      }
    }
  }
}

// ======== i8 GEMM (round-14 verified score_i8 v3 body, geometry generalized) ========
// 128x128 tile, 4 waves (2Mx2N), wave tile 64x64, 64KB LDS -> 2 blocks/CU.
// 4-granule XOR swizzle on 64B rows (conflict-free, verified). 3 passes/chunk:
// hh->acc0; ah.bl + al.bh -> acc1 (ll dropped). K = 1024 (16 chunks) both uses.
// EPI 0: scores f32 = (acc0*2^16+acc1*2^8)*2^-24   (A,B both @2^12)
// EPI 1: keys i8-planes: v = acc0*2^-13 + acc1*2^-21 + bias, qsplit@2^12
//        (A @2^12, B @2^17 -> product 2^29; float(acc0) exact: acc0 < 2^24)

template<int EPI>
__global__ __launch_bounds__(256, 2) void i8gemm(
    const signed char* __restrict__ Ahp, const signed char* __restrict__ Alp,
    const signed char* __restrict__ Bhp, const signed char* __restrict__ Blp,
    int lda, int ldb, int MBLK, int NBLK,
    size_t a_bs, size_t b_bs,
    float* __restrict__ C, int ldc, size_t c_bs,
    const float* __restrict__ bias,
    signed char* __restrict__ oh, signed char* __restrict__ ol)
{
  __shared__ char lds[65536];
  const int tid  = threadIdx.x;
  const int w    = tid >> 6;
  const int lane = tid & 63;
  const int wr = w >> 1, wc = w & 1;
  const int lr = lane & 15, lg = lane >> 4;

  const int nwg = gridDim.x;                 // %8==0
  const int wg  = (blockIdx.x & 7) * (nwg >> 3) + (blockIdx.x >> 3);
  const int per = MBLK * NBLK;
  const int b   = wg / per;
  const int rr  = wg - b * per;
  const int m0  = (rr / NBLK) * 128;
  const int n0  = (rr % NBLK) * 128;

  const signed char* Ah_g = Ahp + b * a_bs + (size_t)m0 * lda;
  const signed char* Al_g = Alp + b * a_bs + (size_t)m0 * lda;
  const signed char* Bh_g = Bhp + b * b_bs + (size_t)n0 * ldb;
  const signed char* Bl_g = Blp + b * b_bs + (size_t)n0 * ldb;
  const int wu = __builtin_amdgcn_readfirstlane(w);

  i32x4 acc0[4][4], acc1[4][4];
#pragma unroll
  for (int m = 0; m < 4; ++m)
#pragma unroll
    for (int n = 0; n < 4; ++n){ acc0[m][n] = (i32x4){0,0,0,0}; acc1[m][n] = (i32x4){0,0,0,0}; }

  auto STAGE = [&](int t, int buf){
    const int k0 = t * 64;
    char* L = lds + buf * 32768;
#pragma unroll
    for (int j = 0; j < 2; ++j){
      int row = wu * 32 + j * 16 + (lane >> 2);
      int g = (lane & 3) ^ ((row >> 1) & 3);
      char* d = L + wu * 2048 + j * 1024;
      gload16(Ah_g + (size_t)row * lda + k0 + g * 16, d);
      gload16(Al_g + (size_t)row * lda + k0 + g * 16, d + 8192);
      gload16(Bh_g + (size_t)row * ldb + k0 + g * 16, d + 16384);
      gload16(Bl_g + (size_t)row * ldb + k0 + g * 16, d + 24576);
    }
  };

  STAGE(0, 0);

  for (int t = 0; t < 16; ++t){
    asm volatile("s_waitcnt vmcnt(0)" ::: "memory");
    __builtin_amdgcn_s_barrier();
    __builtin_amdgcn_sched_barrier(0);
    if (t + 1 < 16) STAGE(t + 1, (t + 1) & 1);
    __builtin_amdgcn_sched_barrier(0);

    const char* L = lds + (t & 1) * 32768;
    i32x4 ah[4], al[4], bh[4], bl[4];
#pragma unroll
    for (int mm = 0; mm < 4; ++mm){
      int row = wr * 64 + mm * 16 + lr;
      int off = row * 64 + ((lg ^ ((row >> 1) & 3)) << 4);
      ah[mm] = *(const i32x4*)(L + off);
      al[mm] = *(const i32x4*)(L + 8192 + off);
    }
#pragma unroll
    for (int nn = 0; nn < 4; ++nn){
      int row = wc * 64 + nn * 16 + lr;
      int off = row * 64 + ((lg ^ ((row >> 1) & 3)) << 4);
      bh[nn] = *(const i32x4*)(L + 16384 + off);
      bl[nn] = *(const i32x4*)(L + 24576 + off);
    }
    __builtin_amdgcn_s_setprio(1);
#pragma unroll
    for (int mm = 0; mm < 4; ++mm)
#pragma unroll
      for (int nn = 0; nn < 4; ++nn)
        acc0[mm][nn] = mfma_i8(ah[mm], bh[nn], acc0[mm][nn]);
#pragma unroll
    for (int mm = 0; mm < 4; ++mm)
#pragma unroll
      for (int nn = 0; nn < 4; ++nn){
        acc1[mm][nn] = mfma_i8(ah[mm], bl[nn], acc1[mm][nn]);
        acc1[mm][nn] = mfma_i8(al[mm], bh[nn], acc1[mm][nn]);
      }
    __builtin_amdgcn_s_setprio(0);
  }

#pragma unroll
  for (int mm = 0; mm < 4; ++mm){
    int grow = m0 + wr * 64 + mm * 16 + lg * 4;
#pragma unroll
    for (int nn = 0; nn < 4; ++nn){
      int gcol = n0 + wc * 64 + nn * 16 + lr;
      if (EPI == 0){
        const float inv = 5.9604644775390625e-8f;   // 2^-24
#pragma unroll
        for (int j = 0; j < 4; ++j)
          C[b * c_bs + (size_t)(grow + j) * ldc + gcol] =
            ((float)acc0[mm][nn][j] * 65536.f + (float)acc1[mm][nn][j] * 256.f) * inv;
      } else {
        float bv = bias[gcol];
#pragma unroll
        for (int j = 0; j < 4; ++j){
          float v = (float)acc0[mm][nn][j] * 1.220703125e-4f        // 2^-13
                  + (float)acc1[mm][nn][j] * 4.76837158203125e-7f   // 2^-21
                  + bv;
          signed char qh, ql;
          qsplit(v, qh, ql);
          size_t idx = (size_t)(grow + j) * ldc + gcol;
          oh[idx] = qh;
          ol[idx] = ql;
        }
      }
    }
  }
}

// ---------------- legacy staging / compute (fallback tiers) ----------------

DEV void stage_raw(char* L, const unsigned short* src, int lda, int tid){
#pragma unroll
  for (int i = 0; i < 4; ++i){
    int chunk = i * 256 + tid;
    int row = chunk >> 3;
    int c8 = (chunk & 7) << 3;
    u32x4 v = *(const u32x4*)(src + (size_t)row * lda + c8);
    *(u32x4*)(L + row * 128 + swzb(row, c8 << 1)) = v;
  }
}

DEV void stage_f32_split(char* Lhi, char* Llo, const float* src, int lda, int tid){
#pragma unroll
  for (int i = 0; i < 8; ++i){
    int chunk = i * 256 + tid;
    int row = chunk >> 4;
    int c4 = (chunk & 15) << 2;
    f32x4 v = *(const f32x4*)(src + (size_t)row * lda + c4);
    unsigned short h0 = f2bf(v[0]), h1 = f2bf(v[1]), h2 = f2bf(v[2]), h3 = f2bf(v[3]);
    u32x2 hw, lw;
    hw[0] = (unsigned)h0 | ((unsigned)h1 << 16); hw[1] = (unsigned)h2 | ((unsigned)h3 << 16);
    lw[0] = (unsigned)f2bf(v[0] - bf2f(h0)) | ((unsigned)f2bf(v[1] - bf2f(h1)) << 16);
    lw[1] = (unsigned)f2bf(v[2] - bf2f(h2)) | ((unsigned)f2bf(v[3] - bf2f(h3)) << 16);
    int off = row * 128 + swzb(row, c4 << 1);
    *(u32x2*)(Lhi + off) = hw;
    *(u32x2*)(Llo + off) = lw;
  }
}

DEV void stage_f32_plain(char* L, const float* src, int lda, int tid){
#pragma unroll
  for (int i = 0; i < 8; ++i){
    int chunk = i * 256 + tid;
    int row = chunk >> 4;
    int c4 = (chunk & 15) << 2;
    f32x4 v = *(const f32x4*)(src + (size_t)row * lda + c4);
    u32x2 hw;
    hw[0] = (unsigned)f2bf(v[0]) | ((unsigned)f2bf(v[1]) << 16);
    hw[1] = (unsigned)f2bf(v[2]) | ((unsigned)f2bf(v[3]) << 16);
    *(u32x2*)(L + row * 128 + swzb(row, c4 << 1)) = hw;
  }
}

DEV void stage_f32_T(char* L, const float* src, int ldb, int tid){
#pragma unroll
  for (int i = 0; i < 8; ++i){
    int mb = i * 256 + tid;
    int np = mb & 63, kp = mb >> 6;
    int gk = kp << 1, gn = np << 1;
    const float* p = src + (size_t)gk * ldb + gn;
    f32x2 r0 = *(const f32x2*)p;
    f32x2 r1 = *(const f32x2*)(p + ldb);
    *(unsigned*)(L + gn * 128 + swzb(gn, gk << 1))           = (unsigned)f2bf(r0[0]) | ((unsigned)f2bf(r1[0]) << 16);
    *(unsigned*)(L + (gn + 1) * 128 + swzb(gn + 1, gk << 1)) = (unsigned)f2bf(r0[1]) | ((unsigned)f2bf(r1[1]) << 16);
  }
}

DEV void compute_split(f32x4 acc[4][4], const char* Ahi, const char* Alo,
                       const char* Bhi, const char* Blo, int wr, int wc, int lane){
  int lr = lane & 15, lg = lane >> 4;
#pragma unroll
  for (int kk = 0; kk < 2; ++kk){
    int cb = kk * 64 + lg * 16;
    bf16x8 ah[4], al[4], bh[4], bl[4];
#pragma unroll
    for (int m = 0; m < 4; ++m){
      int r = wr * 64 + m * 16 + lr;
      ah[m] = *(const bf16x8*)(Ahi + loff(r, cb));
      al[m] = *(const bf16x8*)(Alo + loff(r, cb));
    }
#pragma unroll
    for (int n = 0; n < 4; ++n){
      int r = wc * 64 + n * 16 + lr;
      bh[n] = *(const bf16x8*)(Bhi + loff(r, cb));
      bl[n] = *(const bf16x8*)(Blo + loff(r, cb));
    }
#pragma unroll
    for (int m = 0; m < 4; ++m)
#pragma unroll
      for (int n = 0; n < 4; ++n){
        acc[m][n] = mfma16(ah[m], bh[n], acc[m][n]);
        acc[m][n] = mfma16(al[m], bh[n], acc[m][n]);
        acc[m][n] = mfma16(ah[m], bl[n], acc[m][n]);
      }
  }
}

DEV void compute_plain(f32x4 acc[4][4], const char* A, const char* B, int wr, int wc, int lane){
  int lr = lane & 15, lg = lane >> 4;
#pragma unroll
  for (int kk = 0; kk < 2; ++kk){
    int cb = kk * 64 + lg * 16;
    bf16x8 af[4], bf_[4];
#pragma unroll
    for (int m = 0; m < 4; ++m)
      af[m] = *(const bf16x8*)(A + loff(wr * 64 + m * 16 + lr, cb));
#pragma unroll
    for (int n = 0; n < 4; ++n)
      bf_[n] = *(const bf16x8*)(B + loff(wc * 64 + n * 16 + lr, cb));
#pragma unroll
    for (int m = 0; m < 4; ++m)
#pragma unroll
      for (int n = 0; n < 4; ++n)
        acc[m][n] = mfma16(af[m], bf_[n], acc[m][n]);
  }
}

// ---------------- prep kernels ----------------

// Wa transpose -> bf16 hi/lo planes (fallback tiers)
template<bool SPLIT>
__global__ __launch_bounds__(256) void transpose_prep(
    const float* __restrict__ in, size_t in_bstride, int in_ld,
    unsigned short* __restrict__ oh, unsigned short* __restrict__ ol,
    size_t out_bstride, int out_ld)
{
  __shared__ float T[64][65];
  const int t = threadIdx.x;
  const int r0 = blockIdx.x * 64, c0 = blockIdx.y * 64;
  const float* src = in + (size_t)blockIdx.z * in_bstride;
#pragma unroll
  for (int i = 0; i < 4; ++i){
    int r = (t >> 4) + i * 16;
    int c = (t & 15) * 4;
    f32x4 v = *(const f32x4*)(src + (size_t)(r0 + r) * in_ld + c0 + c);
#pragma unroll
    for (int j = 0; j < 4; ++j) T[r][c + j] = v[j];
  }
  __syncthreads();
#pragma unroll
  for (int i = 0; i < 4; ++i){
    int c = (t >> 4) + i * 16;
    int r = (t & 15) * 4;
    float v0 = T[r][c], v1 = T[r + 1][c], v2 = T[r + 2][c], v3 = T[r + 3][c];
    unsigned short h0 = f2bf(v0), h1 = f2bf(v1), h2 = f2bf(v2), h3 = f2bf(v3);
    u32x2 hw;
    hw[0] = (unsigned)h0 | ((unsigned)h1 << 16);
    hw[1] = (unsigned)h2 | ((unsigned)h3 << 16);
    size_t off = (size_t)blockIdx.z * out_bstride + (size_t)(c0 + c) * out_ld + r0 + r;
    *(u32x2*)(oh + off) = hw;
    if (SPLIT){
      u32x2 lw;
      lw[0] = (unsigned)f2bf(v0 - bf2f(h0)) | ((unsigned)f2bf(v1 - bf2f(h1)) << 16);
      lw[1] = (unsigned)f2bf(v2 - bf2f(h2)) | ((unsigned)f2bf(v3 - bf2f(h3)) << 16);
      *(u32x2*)(ol + off) = lw;
    }
  }
}

// Wa transpose -> i16-as-2xi8 planes at scale 2^17 (fast path)
__global__ __launch_bounds__(256) void wq_prep(
    const float* __restrict__ Wa,
    signed char* __restrict__ wqh, signed char* __restrict__ wql)
{
  __shared__ float T[64][65];
  const int t = threadIdx.x;
  const int r0 = blockIdx.x * 64, c0 = blockIdx.y * 64;   // r = k, c = out-feature
#pragma unroll
  for (int i = 0; i < 4; ++i){
    int r = (t >> 4) + i * 16;
    int c = (t & 15) * 4;
    f32x4 v = *(const f32x4*)(Wa + (size_t)(r0 + r) * 1024 + c0 + c);
#pragma unroll
    for (int j = 0; j < 4; ++j) T[r][c + j] = v[j];
  }
  __syncthreads();
#pragma unroll
  for (int i = 0; i < 4; ++i){
    int c = (t >> 4) + i * 16;     // out-feature
    int r = (t & 15) * 4;          // k group
    unsigned hw = 0, lw = 0;
#pragma unroll
    for (int j = 0; j < 4; ++j){
      signed char qh, ql;
      qsplitS(T[r + j][c], 131072.f, qh, ql);
      hw |= ((unsigned)(unsigned char)qh) << (8 * j);
      lw |= ((unsigned)(unsigned char)ql) << (8 * j);
    }
    size_t off = (size_t)(c0 + c) * 1024 + r0 + r;
    *(unsigned*)(wqh + off) = hw;
    *(unsigned*)(wql + off) = lw;
  }
}

// fused enc prep: one read of enc -> encT (transposed bf16) + eqh/eql (i8 planes @2^12)
__global__ __launch_bounds__(256) void enc_prep(
    const float* __restrict__ enc,
    unsigned short* __restrict__ encT,
    signed char* __restrict__ eqh, signed char* __restrict__ eql)
{
  __shared__ float T[64][65];
  const int t = threadIdx.x;
  const int r0 = blockIdx.x * 64, c0 = blockIdx.y * 64;   // r in 2048, c in 1024
  const int b  = blockIdx.z;
  const float* src = enc + (size_t)b * 2048 * 1024;
#pragma unroll
  for (int i = 0; i < 4; ++i){
    int r = (t >> 4) + i * 16;
    int c = (t & 15) * 4;
    f32x4 v = *(const f32x4*)(src + (size_t)(r0 + r) * 1024 + c0 + c);
#pragma unroll
    for (int j = 0; j < 4; ++j) T[r][c + j] = v[j];
    unsigned hw = 0, lw = 0;
#pragma unroll
    for (int j = 0; j < 4; ++j){
      signed char qh, ql;
      qsplit(v[j], qh, ql);
      hw |= ((unsigned)(unsigned char)qh) << (8 * j);
      lw |= ((unsigned)(unsigned char)ql) << (8 * j);
    }
    size_t roff = ((size_t)b * 2048 + r0 + r) * 1024 + c0 + c;
    *(unsigned*)(eqh + roff) = hw;
    *(unsigned*)(eql + roff) = lw;
  }
  __syncthreads();
#pragma unroll
  for (int i = 0; i < 4; ++i){
    int c = (t >> 4) + i * 16;
    int r = (t & 15) * 4;
    u32x2 hw;
    hw[0] = (unsigned)f2bf(T[r][c])     | ((unsigned)f2bf(T[r + 1][c]) << 16);
    hw[1] = (unsigned)f2bf(T[r + 2][c]) | ((unsigned)f2bf(T[r + 3][c]) << 16);
    *(u32x2*)(encT + (size_t)b * 2097152 + (size_t)(c0 + c) * 2048 + r0 + r) = hw;
  }
}

__global__ __launch_bounds__(256) void quant_prep(
    const float* __restrict__ in, signed char* __restrict__ oh,
    signed char* __restrict__ ol)
{
  size_t i = ((size_t)blockIdx.x * 256 + threadIdx.x) * 8;
  f32x4 a = *(const f32x4*)(in + i);
  f32x4 c = *(const f32x4*)(in + i + 4);
  unsigned hw0 = 0, hw1 = 0, lw0 = 0, lw1 = 0;
#pragma unroll
  for (int j = 0; j < 4; ++j){
    signed char qh, ql;
    qsplit(a[j], qh, ql);
    hw0 |= ((unsigned)(unsigned char)qh) << (8 * j);
    lw0 |= ((unsigned)(unsigned char)ql) << (8 * j);
    qsplit(c[j], qh, ql);
    hw1 |= ((unsigned)(unsigned char)qh) << (8 * j);
    lw1 |= ((unsigned)(unsigned char)ql) << (8 * j);
  }
  u32x2 hv, lv;
  hv[0] = hw0; hv[1] = hw1; lv[0] = lw0; lv[1] = lw1;
  *(u32x2*)(oh + i) = hv;
  *(u32x2*)(ol + i) = lv;
}

// ---------------- legacy kernels (fallback tiers) ----------------

__global__ __launch_bounds__(256, 2) void keys_gemm(
    const float* __restrict__ enc,
    const unsigned short* __restrict__ WaTh, const unsigned short* __restrict__ WaTl,
    const float* __restrict__ bias,
    unsigned short* __restrict__ khi, unsigned short* __restrict__ klo)
{
  __shared__ char lds[65536];
  char *Ahi = lds, *Alo = lds + 16384, *Bhi = lds + 32768, *Blo = lds + 49152;
  const int tid = threadIdx.x;
  const int lane = tid & 63, w = tid >> 6;
  const int wr = w >> 1, wc = w & 1;
  const int lr = lane & 15, lg = lane >> 4;
  const int m0 = blockIdx.y * 128;
  const int n0 = blockIdx.x * 128;

  f32x4 acc[4][4];
#pragma unroll
  for (int m = 0; m < 4; ++m)
#pragma unroll
    for (int n = 0; n < 4; ++n) acc[m][n] = (f32x4){0.f, 0.f, 0.f, 0.f};

  for (int k0 = 0; k0 < 1024; k0 += 64){
    __syncthreads();
    stage_f32_split(Ahi, Alo, enc + (size_t)m0 * 1024 + k0, 1024, tid);
    stage_raw(Bhi, WaTh + (size_t)n0 * 1024 + k0, 1024, tid);
    stage_raw(Blo, WaTl + (size_t)n0 * 1024 + k0, 1024, tid);
    __syncthreads();
    compute_split(acc, Ahi, Alo, Bhi, Blo, wr, wc, lane);
  }

#pragma unroll
  for (int n = 0; n < 4; ++n){
    int col = n0 + wc * 64 + n * 16 + lr;
    float bv = bias[col];
#pragma unroll
    for (int m = 0; m < 4; ++m){
      int rbase = m0 + wr * 64 + m * 16 + lg * 4;
#pragma unroll
      for (int j = 0; j < 4; ++j){
        float v = acc[m][n][j] + bv;
        unsigned short h = f2bf(v);
        size_t idx = (size_t)(rbase + j) * 1024 + col;
        khi[idx] = h;
        klo[idx] = f2bf(v - bf2f(h));
      }
    }
  }
}

template<bool PRESPLIT>
__global__ __launch_bounds__(256, 2) void score_gemm(
    const float* __restrict__ dec,
    const unsigned short* __restrict__ dech, const unsigned short* __restrict__ decl,
    const unsigned short* __restrict__ khi, const unsigned short* __restrict__ klo,
    float* __restrict__ scores)
{
  __shared__ char lds[65536];
  char *Ahi = lds, *Alo = lds + 16384, *Bhi = lds + 32768, *Blo = lds + 49152;
  const int tid = threadIdx.x;
  const int lane = tid & 63, w = tid >> 6;
  const int wr = w >> 1, wc = w & 1;
  const int lr = lane & 15, lg = lane >> 4;
  const int b  = blockIdx.z;
  const int m0 = blockIdx.y * 128;
  const int n0 = blockIdx.x * 128;

  f32x4 acc[4][4];
#pragma unroll
  for (int m = 0; m < 4; ++m)
#pragma unroll
    for (int n = 0; n < 4; ++n) acc[m][n] = (f32x4){0.f, 0.f, 0.f, 0.f};

  const size_t arow = (size_t)b * 2048 + m0;
  const size_t brow = (size_t)b * 2048 + n0;

  for (int k0 = 0; k0 < 1024; k0 += 64){
    __syncthreads();
    if (PRESPLIT){
      stage_raw(Ahi, dech + arow * 1024 + k0, 1024, tid);
      stage_raw(Alo, decl + arow * 1024 + k0, 1024, tid);
    } else {
      stage_f32_split(Ahi, Alo, dec + arow * 1024 + k0, 1024, tid);
    }
    stage_raw(Bhi, khi + brow * 1024 + k0, 1024, tid);
    stage_raw(Blo, klo + brow * 1024 + k0, 1024, tid);
    __syncthreads();
    compute_split(acc, Ahi, Alo, Bhi, Blo, wr, wc, lane);
  }

#pragma unroll
  for (int n = 0; n < 4; ++n){
    int col = n0 + wc * 64 + n * 16 + lr;
#pragma unroll
    for (int m = 0; m < 4; ++m){
      int rbase = m0 + wr * 64 + m * 16 + lg * 4;
#pragma unroll
      for (int j = 0; j < 4; ++j)
        scores[((size_t)b * 2048 + rbase + j) * 2048 + col] = acc[m][n][j];
    }
  }
}

// ---------------- softmax ----------------

template<bool DUALW>
__global__ __launch_bounds__(256, 4) void softmax_k(float* scores, unsigned short* alignb)
{
  const int row = blockIdx.x;
  const int t = threadIdx.x;
  float* src = scores + (size_t)row * 2048;
  f32x4 va = *(const f32x4*)(src + t * 8);
  f32x4 vb = *(const f32x4*)(src + t * 8 + 4);
  float f[8];
#pragma unroll
  for (int j = 0; j < 4; ++j){ f[j] = va[j]; f[4 + j] = vb[j]; }
  float m = -3.0e38f;
#pragma unroll
  for (int j = 0; j < 8; ++j) m = fmaxf(m, f[j]);
#pragma unroll
  for (int o = 1; o < 64; o <<= 1) m = fmaxf(m, __shfl_xor(m, o));
  __shared__ float red[4];
  const int wid = t >> 6;
  if ((t & 63) == 0) red[wid] = m;
  __syncthreads();
  m = fmaxf(fmaxf(red[0], red[1]), fmaxf(red[2], red[3]));
  float p[8]; float s = 0.f;
#pragma unroll
  for (int j = 0; j < 8; ++j){ p[j] = __expf(f[j] - m); s += p[j]; }
#pragma unroll
  for (int o = 1; o < 64; o <<= 1) s += __shfl_xor(s, o);
  __syncthreads();
  if ((t & 63) == 0) red[wid] = s;
  __syncthreads();
  s = (red[0] + red[1]) + (red[2] + red[3]);
  float inv = 1.0f / s;
  f32x4 oa, ob;
#pragma unroll
  for (int j = 0; j < 4; ++j){ oa[j] = p[j] * inv; ob[j] = p[4 + j] * inv; }
  *(f32x4*)(src + t * 8)     = oa;
  *(f32x4*)(src + t * 8 + 4) = ob;
  if (DUALW){
    u32x4 wv;
#pragma unroll
    for (int j = 0; j < 4; ++j){
      float x0 = (j < 2) ? oa[2 * j] : ob[2 * j - 4];
      float x1 = (j < 2) ? oa[2 * j + 1] : ob[2 * j - 3];
      wv[j] = (unsigned)f2bf(x0) | ((unsigned)f2bf(x1) << 16);
    }
    *(u32x4*)(alignb + (size_t)row * 2048 + t * 8) = wv;
  }
}

// ---------------- legacy ctx kernels (fallback tiers) ----------------

__global__ __launch_bounds__(256, 3) void ctx_gemm_fast(
    const unsigned short* __restrict__ alignb,
    const unsigned short* __restrict__ encT,
    float* __restrict__ ctx)
{
  __shared__ char lds[32768];
  char *A = lds, *B = lds + 16384;
  const int tid = threadIdx.x;
  const int lane = tid & 63, w = tid >> 6;
  const int wr = w >> 1, wc = w & 1;
  const int lr = lane & 15, lg = lane >> 4;
  const int wg = blockIdx.x;
  const int n0 = (wg & 7) * 128;
  const int m0 = ((wg >> 3) & 15) * 128;
  const int b  = wg >> 7;

  const unsigned short* Asrc = alignb + ((size_t)b * 2048 + m0) * 2048;
  const unsigned short* Bsrc = encT   + (size_t)b * 2097152 + (size_t)n0 * 2048;

  f32x4 acc[4][4];
#pragma unroll
  for (int m = 0; m < 4; ++m)
#pragma unroll
    for (int n = 0; n < 4; ++n) acc[m][n] = (f32x4){0.f, 0.f, 0.f, 0.f};

  const int row_ = tid >> 3;
  const int c8_  = (tid & 7) << 3;

  u32x4 ra[4], rb[4];
#pragma unroll
  for (int i = 0; i < 4; ++i){
    int row = row_ + i * 32;
    ra[i] = *(const u32x4*)(Asrc + (size_t)row * 2048 + c8_);
    rb[i] = *(const u32x4*)(Bsrc + (size_t)row * 2048 + c8_);
  }

  for (int t = 0; t < 32; ++t){
    __syncthreads();
#pragma unroll
    for (int i = 0; i < 4; ++i){
      int row = row_ + i * 32;
      int off = row * 128 + swzb(row, c8_ << 1);
      *(u32x4*)(A + off) = ra[i];
      *(u32x4*)(B + off) = rb[i];
    }
    __syncthreads();
    if (t + 1 < 32){
      int k0 = (t + 1) * 64;
#pragma unroll
      for (int i = 0; i < 4; ++i){
        int row = row_ + i * 32;
        ra[i] = *(const u32x4*)(Asrc + (size_t)row * 2048 + k0 + c8_);
        rb[i] = *(const u32x4*)(Bsrc + (size_t)row * 2048 + k0 + c8_);
      }
    }
    compute_plain(acc, A, B, wr, wc, lane);
  }

#pragma unroll
  for (int n = 0; n < 4; ++n){
    int col = n0 + wc * 64 + n * 16 + lr;
#pragma unroll
    for (int m = 0; m < 4; ++m){
      int rbase = m0 + wr * 64 + m * 16 + lg * 4;
#pragma unroll
      for (int j = 0; j < 4; ++j)
        ctx[((size_t)b * 2048 + rbase + j) * 1024 + col] = acc[m][n][j];
    }
  }
}

template<bool TRANS_WS>
__global__ __launch_bounds__(256, 2) void ctx_gemm(
    const float* __restrict__ alignf,
    const float* __restrict__ enc, const unsigned short* __restrict__ encT,
    float* __restrict__ ctx)
{
  __shared__ char lds[32768];
  char *A = lds, *B = lds + 16384;
  const int tid = threadIdx.x;
  const int lane = tid & 63, w = tid >> 6;
  const int wr = w >> 1, wc = w & 1;
  const int lr = lane & 15, lg = lane >> 4;
  const int b  = blockIdx.z;
  const int m0 = blockIdx.y * 128;
  const int n0 = blockIdx.x * 128;

  f32x4 acc[4][4];
#pragma unroll
  for (int m = 0; m < 4; ++m)
#pragma unroll
    for (int n = 0; n < 4; ++n) acc[m][n] = (f32x4){0.f, 0.f, 0.f, 0.f};

  const float* Asrc = alignf + ((size_t)b * 2048 + m0) * 2048;

  for (int k0 = 0; k0 < 2048; k0 += 64){
    __syncthreads();
    stage_f32_plain(A, Asrc + k0, 2048, tid);
    if (TRANS_WS)
      stage_raw(B, encT + (size_t)b * 2097152 + (size_t)n0 * 2048 + k0, 2048, tid);
    else
      stage_f32_T(B, enc + ((size_t)b * 2048 + k0) * 1024 + n0, 1024, tid);
    __syncthreads();
    compute_plain(acc, A, B, wr, wc, lane);
  }

#pragma unroll
  for (int n = 0; n < 4; ++n){
    int col = n0 + wc * 64 + n * 16 + lr;
#pragma unroll
    for (int m = 0; m < 4; ++m){
      int rbase = m0 + wr * 64 + m * 16 + lg * 4;
#pragma unroll
      for (int j = 0; j < 4; ++j)
        ctx[((size_t)b * 2048 + rbase + j) * 1024 + col] = acc[m][n][j];
    }
  }
}

// ---------------- launch ----------------
// Fast path (ws >= 167,772,160 B):
//   ws: dqh|dql|eqh|eql (16.8 MB each) | encT bf16 (33.5) | alignb bf16 (67) = 167.8 exactly.
//   wqh/wql (Wa^T i8 @2^17, 1 MB each) in align tail; kqh/kql in ctx region.
//   keys  = i8gemm<1> (enc@2^12 x WaT@2^17 -> i8 key planes + bias)
//   score = i8gemm<0> (dec@2^12 x keys@2^12 -> f32 scores)
//   ctx   = gemm_big<1,0> bf16 (verified).

extern "C" void kernel_launch(void* const* d_in, const int* in_sizes, int n_in,
                              void* d_out, int out_size, void* d_ws, size_t ws_size,
                              hipStream_t stream) {
  const float* enc  = (const float*)d_in[0];
  const float* dec  = (const float*)d_in[1];
  const float* Wa   = (const float*)d_in[2];
  const float* bias = (const float*)d_in[3];

  float* out    = (float*)d_out;
  float* ctx    = out;
  float* alignf = out + (size_t)8 * 2048 * 1024;
  float* scores = alignf;

  const size_t NKEY    = (size_t)16384 * 1024;
  const size_t ENCT_B  = NKEY * 2;
  const size_t ALIGNB_B= (size_t)8 * 2048 * 2048 * 2;
  const size_t DECP_B  = NKEY * 2;
  bool has_encT   = ws_size >= ENCT_B;
  bool has_alignb = ws_size >= ENCT_B + ALIGNB_B;
  bool has_decp   = ws_size >= ENCT_B + ALIGNB_B + 2 * DECP_B;

  if (has_decp){
    signed char* dqh = (signed char*)d_ws;                        // 16.8 MB
    signed char* dql = dqh + NKEY;                                // 16.8
    signed char* eqh = dql + NKEY;                                // 16.8
    signed char* eql = eqh + NKEY;                                // 16.8
    unsigned short* encT   = (unsigned short*)(eql + NKEY);       // 33.5
    unsigned short* alignb = encT + (size_t)8 * 1024 * 2048;      // 67

    signed char* kqh = (signed char*)ctx;                         // keys i8 planes
    signed char* kql = kqh + NKEY;

    signed char* wqh = (signed char*)(alignf + 32505856);         // Wa^T i8 planes
    signed char* wql = wqh + (size_t)1024 * 1024;                 // (align tail, 2 MB)

    wq_prep<<<dim3(16, 16), 256, 0, stream>>>(Wa, wqh, wql);
    enc_prep<<<dim3(32, 16, 8), 256, 0, stream>>>(enc, encT, eqh, eql);
    quant_prep<<<dim3(8192), 256, 0, stream>>>(dec, dqh, dql);

    // keys: M=16384 (128 blk) x N=1024 (8 blk), K=1024
    i8gemm<1><<<1024, 256, 0, stream>>>(
        eqh, eql, wqh, wql, 1024, 1024, 128, 8,
        0, 0, nullptr, 1024, 0, bias, kqh, kql);

    // score: per batch M=2048 (16) x N=2048 (16), K=1024
    i8gemm<0><<<2048, 256, 0, stream>>>(
        dqh, dql, kqh, kql, 1024, 1024, 16, 16,
        (size_t)2048 * 1024, (size_t)2048 * 1024,
        scores, 2048, (size_t)2048 * 2048, nullptr, nullptr, nullptr);

    softmax_k<true><<<dim3(16384), 256, 0, stream>>>(scores, alignb);

    gemm_big<1, 0><<<256, 512, 0, stream>>>(
        alignb, alignb, encT, encT, 2048, 2048, 8, 4, 32,
        (size_t)2048 * 2048, (size_t)1024 * 2048, ctx, 1024, (size_t)2048 * 1024,
        nullptr, nullptr, nullptr);
  } else {
    unsigned short* khi = (unsigned short*)ctx;
    unsigned short* klo = khi + NKEY;
    unsigned short* encT   = (unsigned short*)d_ws;
    unsigned short* alignb = (unsigned short*)((char*)d_ws + ENCT_B);

    unsigned short* WaTh = (unsigned short*)(alignf + 32505856);
    unsigned short* WaTl = WaTh + (size_t)1024 * 1024;

    transpose_prep<true><<<dim3(16, 16, 1), 256, 0, stream>>>(
        Wa, 0, 1024, WaTh, WaTl, 0, 1024);
    if (has_encT)
      transpose_prep<false><<<dim3(32, 16, 8), 256, 0, stream>>>(
          enc, (size_t)2048 * 1024, 1024, encT, nullptr, (size_t)1024 * 2048, 2048);

    keys_gemm<<<dim3(8, 128), 256, 0, stream>>>(enc, WaTh, WaTl, bias, khi, klo);
    score_gemm<false><<<dim3(16, 16, 8), 256, 0, stream>>>(dec, nullptr, nullptr, khi, klo, scores);

    if (has_alignb){
      softmax_k<true><<<dim3(16384), 256, 0, stream>>>(scores, alignb);
      ctx_gemm_fast<<<dim3(1024), 256, 0, stream>>>(alignb, encT, ctx);
    } else {
      softmax_k<false><<<dim3(16384), 256, 0, stream>>>(scores, nullptr);
      if (has_encT)
        ctx_gemm<true><<<dim3(8, 16, 8), 256, 0, stream>>>(alignf, nullptr, encT, ctx);
      else
        ctx_gemm<false><<<dim3(8, 16, 8), 256, 0, stream>>>(alignf, enc, nullptr, ctx);
    }
  }
}